// Round 1
// baseline (2986.742 us; speedup 1.0000x reference)
//
#include <hip/hip_runtime.h>
#include <hip/hip_bf16.h>
#include <math.h>

// ---------------------------------------------------------------------------
// Problem constants
// ---------------------------------------------------------------------------
#define N_PQ 65536
#define N_PV 16384
#define N_SL 64
#define KDIM 128

// ---------------------------------------------------------------------------
// GEMM: C[M,128] = A[M,128] @ W[128,128] + bias   (fp32, correctness-first)
// 16 rows per block, 256 threads. W staged in LDS in two 64-row chunks.
// ---------------------------------------------------------------------------
__global__ __launch_bounds__(256) void gemm_k128(
    const float* __restrict__ A, const float* __restrict__ W,
    const float* __restrict__ bias, float* __restrict__ C, int M)
{
    __shared__ float Wl[64 * 128];
    __shared__ float Al[16 * 128];
    const int tid  = threadIdx.x;
    const int row0 = blockIdx.x * 16;

    for (int i = tid; i < 16 * 128; i += 256) {
        int r = i >> 7, c = i & 127;
        int gr = row0 + r;
        Al[i] = (gr < M) ? A[gr * 128 + c] : 0.f;
    }

    const int j    = tid & 127;
    const int half = tid >> 7;   // 0..1 -> rows half*8 .. half*8+7
    float acc[8] = {0.f, 0.f, 0.f, 0.f, 0.f, 0.f, 0.f, 0.f};

    for (int kc = 0; kc < 2; ++kc) {
        __syncthreads();
        for (int i = tid; i < 64 * 128; i += 256) Wl[i] = W[kc * 8192 + i];
        __syncthreads();
        #pragma unroll 4
        for (int k = 0; k < 64; ++k) {
            float w = Wl[k * 128 + j];
            #pragma unroll
            for (int r = 0; r < 8; ++r)
                acc[r] += Al[(half * 8 + r) * 128 + (kc * 64 + k)] * w;
        }
    }

    float bv = bias ? bias[j] : 0.f;
    #pragma unroll
    for (int r = 0; r < 8; ++r) {
        int gr = row0 + half * 8 + r;
        if (gr < M) C[gr * 128 + j] = acc[r] + bv;
    }
}

// ---------------------------------------------------------------------------
// Global-feature pooling: gnode[b,0,:]=mean_i gf[b,i,:], gnode[b,1,:]=max
// gf laid out as [PQ(65536) ; PV(16384) ; SL(64)] x 128
// ---------------------------------------------------------------------------
__global__ void gnode_reduce(const float* __restrict__ gf, float* __restrict__ gn)
{
    const int b = blockIdx.x;
    const int j = threadIdx.x;   // 128 threads
    float s = 0.f, m = -INFINITY;
    const float* pq = gf + (size_t)(b * 1024) * 128;
    for (int i = 0; i < 1024; ++i) { float v = pq[i * 128 + j]; s += v; m = fmaxf(m, v); }
    const float* pv = gf + (size_t)(N_PQ + b * 256) * 128;
    for (int i = 0; i < 256; ++i)  { float v = pv[i * 128 + j]; s += v; m = fmaxf(m, v); }
    { float v = gf[(size_t)(N_PQ + N_PV + b) * 128 + j]; s += v; m = fmaxf(m, v); }
    gn[(size_t)(b * 2) * 128 + j]     = s * (1.f / 1281.f);
    gn[(size_t)(b * 2 + 1) * 128 + j] = m;
}

// ---------------------------------------------------------------------------
// Per-layer sum of Ws / bconv over edge types sharing a destination.
// dst(t) = {0,1,2,0,1,2,0,1}
// ---------------------------------------------------------------------------
__global__ void sum_ws(const float* __restrict__ Ws, const float* __restrict__ bc,
                       int l, float* __restrict__ wss, float* __restrict__ bss)
{
    const int i = blockIdx.x * 256 + threadIdx.x;
    const int dsts[8] = {0, 1, 2, 0, 1, 2, 0, 1};
    if (i < 16384) {
        float a0 = 0.f, a1 = 0.f, a2 = 0.f;
        #pragma unroll
        for (int t = 0; t < 8; ++t) {
            float w = Ws[(size_t)(l * 8 + t) * 16384 + i];
            if (dsts[t] == 0) a0 += w; else if (dsts[t] == 1) a1 += w; else a2 += w;
        }
        wss[i] = a0; wss[16384 + i] = a1; wss[32768 + i] = a2;
    }
    if (i < 128) {
        float a0 = 0.f, a1 = 0.f, a2 = 0.f;
        #pragma unroll
        for (int t = 0; t < 8; ++t) {
            float w = bc[(size_t)(l * 8 + t) * 128 + i];
            if (dsts[t] == 0) a0 += w; else if (dsts[t] == 1) a1 += w; else a2 += w;
        }
        bss[i] = a0; bss[128 + i] = a1; bss[256 + i] = a2;
    }
}

// ---------------------------------------------------------------------------
// Edge kernel: 128 threads per edge (2 edges / 256-thread block).
// e_ = ea @ We + be computed on the fly (16 MACs / output feature).
// gate = sigmoid(k[dst] + q[src] + e_); atomicAdd(new[dst], gate * v[src])
// ---------------------------------------------------------------------------
__global__ __launch_bounds__(256) void edge_kernel(
    const int* __restrict__ ei, const float* __restrict__ ea,
    const float* __restrict__ We, const float* __restrict__ be,
    const float* __restrict__ kb, const float* __restrict__ qb,
    const float* __restrict__ vb, float* __restrict__ nd, int E)
{
    const int e = blockIdx.x * 2 + (threadIdx.x >> 7);
    if (e >= E) return;
    const int j  = threadIdx.x & 127;
    const int si = ei[e];
    const int di = ei[E + e];

    float ej = be[j];
    #pragma unroll
    for (int r = 0; r < 16; ++r)
        ej += ea[(size_t)e * 16 + r] * We[r * 128 + j];

    float xg   = kb[(size_t)di * 128 + j] + qb[(size_t)si * 128 + j] + ej;
    float gate = 1.f / (1.f + __expf(-xg));
    atomicAdd(&nd[(size_t)di * 128 + j], gate * vb[(size_t)si * 128 + j]);
}

// ---------------------------------------------------------------------------
// ReLU: cur = max(new, 0)
// ---------------------------------------------------------------------------
__global__ void relu_kernel(const float* __restrict__ a, float* __restrict__ o, int n)
{
    int i = blockIdx.x * 256 + threadIdx.x;
    if (i < n) o[i] = fmaxf(a[i], 0.f);
}

// ---------------------------------------------------------------------------
// Cross-attention (2 keys): ao[n] = softmax(q.k/4) @ v ; 128 threads / node
// ---------------------------------------------------------------------------
__global__ __launch_bounds__(256) void attn_kernel(
    const float* __restrict__ q, const float* __restrict__ k2,
    const float* __restrict__ v2, float* __restrict__ ao, int N1, int Ntot)
{
    const int n = blockIdx.x * 2 + (threadIdx.x >> 7);
    if (n >= Ntot) return;
    const int j   = threadIdx.x & 127;
    const int b   = n / N1;
    const int h16 = j & ~15;   // head base

    const float* qn = q  + (size_t)n * 128 + h16;
    const float* k0 = k2 + (size_t)(b * 2) * 128 + h16;
    const float* k1 = k2 + (size_t)(b * 2 + 1) * 128 + h16;
    float s0 = 0.f, s1 = 0.f;
    #pragma unroll
    for (int d = 0; d < 16; ++d) { float qq = qn[d]; s0 += qq * k0[d]; s1 += qq * k1[d]; }
    s0 *= 0.25f; s1 *= 0.25f;
    float m  = fmaxf(s0, s1);
    float a0 = __expf(s0 - m), a1 = __expf(s1 - m);
    float inv = 1.f / (a0 + a1);
    ao[(size_t)n * 128 + j] =
        (a0 * v2[(size_t)(b * 2) * 128 + j] + a1 * v2[(size_t)(b * 2 + 1) * 128 + j]) * inv;
}

// ---------------------------------------------------------------------------
// LayerNorm: out = LN(x + ca) * g + b ; one 64-lane wave per node (2 feat/lane)
// ---------------------------------------------------------------------------
__global__ __launch_bounds__(256) void ln_kernel(
    const float* __restrict__ x, const float* __restrict__ ca,
    const float* __restrict__ g, const float* __restrict__ bb,
    float* __restrict__ out, int N)
{
    const int n = blockIdx.x * 4 + (threadIdx.x >> 6);
    if (n >= N) return;
    const int l  = threadIdx.x & 63;
    const size_t base = (size_t)n * 128;
    float h0 = x[base + l * 2]     + ca[base + l * 2];
    float h1 = x[base + l * 2 + 1] + ca[base + l * 2 + 1];
    float s  = h0 + h1;
    float ss = h0 * h0 + h1 * h1;
    #pragma unroll
    for (int o = 32; o; o >>= 1) { s += __shfl_xor(s, o); ss += __shfl_xor(ss, o); }
    float mu  = s * (1.f / 128.f);
    float var = ss * (1.f / 128.f) - mu * mu;
    float rs  = rsqrtf(var + 1e-5f);
    out[base + l * 2]     = (h0 - mu) * rs * g[l * 2]     + bb[l * 2];
    out[base + l * 2 + 1] = (h1 - mu) * rs * g[l * 2 + 1] + bb[l * 2 + 1];
}

__global__ void copy_kernel(const float* __restrict__ a, float* __restrict__ o, int n)
{
    int i = blockIdx.x * 256 + threadIdx.x;
    if (i < n) o[i] = a[i];
}

// ---------------------------------------------------------------------------
// Host orchestration
// ---------------------------------------------------------------------------
extern "C" void kernel_launch(void* const* d_in, const int* in_sizes, int n_in,
                              void* d_out, int out_size, void* d_ws, size_t ws_size,
                              hipStream_t stream)
{
    const float* xin[3] = {(const float*)d_in[0], (const float*)d_in[1], (const float*)d_in[2]};
    const int NNs[3] = {N_PQ, N_PV, N_SL};

    const int*   ei[8];
    const float* ea[8];
    int          Ecnt[8];
    for (int t = 0; t < 8; ++t) {
        ei[t]   = (const int*)d_in[3 + 2 * t];
        ea[t]   = (const float*)d_in[4 + 2 * t];
        Ecnt[t] = in_sizes[3 + 2 * t] / 2;
    }
    const float* Wk    = (const float*)d_in[19];
    const float* bk    = (const float*)d_in[20];
    const float* Wq    = (const float*)d_in[21];
    const float* bq    = (const float*)d_in[22];
    const float* Wv    = (const float*)d_in[23];
    const float* bv    = (const float*)d_in[24];
    const float* Ws    = (const float*)d_in[25];
    const float* bconv = (const float*)d_in[26];
    const float* We    = (const float*)d_in[27];
    const float* be    = (const float*)d_in[28];
    const float* Wgt   = (const float*)d_in[29];
    const float* bgt   = (const float*)d_in[30];
    const float* Wq1   = (const float*)d_in[31];
    const float* Wk2   = (const float*)d_in[32];
    const float* Wv2   = (const float*)d_in[33];
    const float* Wo    = (const float*)d_in[34];
    const float* bo    = (const float*)d_in[35];
    const float* ln_g  = (const float*)d_in[36];
    const float* ln_b  = (const float*)d_in[37];

    // workspace carve-up (fp32 elements)
    float* p    = (float*)d_ws;
    float* kbuf = p; p += (size_t)N_PQ * 128;
    float* qbuf = p; p += (size_t)N_PQ * 128;
    float* vbuf = p; p += (size_t)N_PQ * 128;
    float* cur[3];
    cur[0] = p; p += (size_t)N_PQ * 128;
    cur[1] = p; p += (size_t)N_PV * 128;
    cur[2] = p; p += (size_t)N_SL * 128;
    float* nw[3];
    nw[0] = p; p += (size_t)N_PQ * 128;
    nw[1] = p; p += (size_t)N_PV * 128;
    nw[2] = p; p += (size_t)N_SL * 128;
    float* gnode = p; p += 64 * 2 * 128;
    float* k2    = p; p += 64 * 2 * 128;
    float* v2    = p; p += 64 * 2 * 128;
    float* wss   = p; p += 3 * 16384;
    float* bss   = p; p += 3 * 128;
    float* gf    = kbuf;  // overlay: 81984*128 floats fit inside kbuf+qbuf

    auto gemm = [&](const float* A, const float* W, const float* bias, float* C, int M) {
        gemm_k128<<<dim3((M + 15) / 16), 256, 0, stream>>>(A, W, bias, C, M);
    };

    // 1) global features + pooling (from ORIGINAL inputs)
    gemm(xin[0], Wgt, bgt, gf, N_PQ);
    gemm(xin[1], Wgt, bgt, gf + (size_t)N_PQ * 128, N_PV);
    gemm(xin[2], Wgt, bgt, gf + (size_t)(N_PQ + N_PV) * 128, N_SL);
    gnode_reduce<<<64, 128, 0, stream>>>(gf, gnode);
    gemm(gnode, Wk2, nullptr, k2, 128);
    gemm(gnode, Wv2, nullptr, v2, 128);

    // 2) two HeteroConv layers
    const int srcs[8] = {0, 0, 0, 1, 1, 1, 2, 2};
    const int dsts[8] = {0, 1, 2, 0, 1, 2, 0, 1};
    const float* xp[3] = {xin[0], xin[1], xin[2]};
    for (int l = 0; l < 2; ++l) {
        sum_ws<<<64, 256, 0, stream>>>(Ws, bconv, l, wss, bss);
        for (int d = 0; d < 3; ++d)
            gemm(xp[d], wss + d * 16384, bss + d * 128, nw[d], NNs[d]);
        for (int t = 0; t < 8; ++t) {
            const int s = srcs[t], d = dsts[t], off = l * 8 + t;
            gemm(xp[d], Wk + (size_t)off * 16384, bk + (size_t)off * 128, kbuf, NNs[d]);
            gemm(xp[s], Wq + (size_t)off * 16384, bq + (size_t)off * 128, qbuf, NNs[s]);
            gemm(xp[s], Wv + (size_t)off * 16384, bv + (size_t)off * 128, vbuf, NNs[s]);
            edge_kernel<<<dim3((Ecnt[t] + 1) / 2), 256, 0, stream>>>(
                ei[t], ea[t], We + (size_t)off * 2048, be + (size_t)off * 128,
                kbuf, qbuf, vbuf, nw[d], Ecnt[t]);
        }
        for (int d = 0; d < 3; ++d) {
            int n = NNs[d] * 128;
            relu_kernel<<<dim3((n + 255) / 256), 256, 0, stream>>>(nw[d], cur[d], n);
        }
        xp[0] = cur[0]; xp[1] = cur[1]; xp[2] = cur[2];
    }

    // 3) cross-attention + residual + LayerNorm (PQ, PV)
    float* outp = (float*)d_out;
    // PQ
    gemm(cur[0], Wq1, nullptr, qbuf, N_PQ);
    attn_kernel<<<dim3(N_PQ / 2), 256, 0, stream>>>(qbuf, k2, v2, vbuf, 1024, N_PQ);
    gemm(vbuf, Wo, bo, kbuf, N_PQ);
    ln_kernel<<<dim3(N_PQ / 4), 256, 0, stream>>>(cur[0], kbuf, ln_g, ln_b, outp, N_PQ);
    // PV
    gemm(cur[1], Wq1, nullptr, qbuf, N_PV);
    attn_kernel<<<dim3(N_PV / 2), 256, 0, stream>>>(qbuf, k2, v2, vbuf, 256, N_PV);
    gemm(vbuf, Wo, bo, kbuf, N_PV);
    ln_kernel<<<dim3(N_PV / 4), 256, 0, stream>>>(cur[1], kbuf, ln_g, ln_b,
                                                  outp + (size_t)N_PQ * 128, N_PV);
    // Slack passthrough (post-conv state)
    copy_kernel<<<dim3((N_SL * 128 + 255) / 256), 256, 0, stream>>>(
        cur[2], outp + (size_t)(N_PQ + N_PV) * 128, N_SL * 128);
}

// Round 2
// 1449.146 us; speedup vs baseline: 2.0610x; 2.0610x over previous
//
#include <hip/hip_runtime.h>
#include <hip/hip_bf16.h>
#include <math.h>

#define N_PQ 65536
#define N_PV 16384
#define N_SL 64

typedef __attribute__((ext_vector_type(8))) short s16x8;
typedef __attribute__((ext_vector_type(4))) float f32x4;

__device__ __forceinline__ ushort f2bf(float f) {
    union { float f; unsigned u; } x; x.f = f;
    unsigned r = x.u + 0x7fff + ((x.u >> 16) & 1);
    return (ushort)(r >> 16);
}
__device__ __forceinline__ float bf2f(ushort u) {
    union { unsigned u; float f; } x; x.u = ((unsigned)u) << 16;
    return x.f;
}

// ---------------------------------------------------------------------------
// MFMA GEMM: C[M,N] = A[M,128](bf16) @ Bt[N,128](bf16, n-major) + bias
// 128x128 tile, 4 waves (2x2), each wave 64x64 (4x4 frags of 16x16x32).
// OUT_BF16=1 -> C ushort (LDS-transposed coalesced store); else float.
// ---------------------------------------------------------------------------
template<int OUT_BF16>
__global__ __launch_bounds__(256) void gemm_mfma(
    const ushort* __restrict__ A, const ushort* __restrict__ Bt,
    const float* __restrict__ bias, void* __restrict__ Cv, int M, int N)
{
    __shared__ ushort As[128 * 128];   // 32 KB, XOR-swizzled by 16B unit
    const int tid = threadIdx.x;
    const int m0 = blockIdx.x * 128;
    const int n0 = blockIdx.y * 128;

    #pragma unroll
    for (int p = 0; p < 8; ++p) {
        int c = p * 256 + tid;
        int row = c >> 4, c16 = c & 15;
        int gr = m0 + row;
        int4 v = make_int4(0, 0, 0, 0);
        if (gr < M) v = *(const int4*)(A + (size_t)gr * 128 + c16 * 8);
        *(int4*)(As + row * 128 + (c16 ^ (row & 7)) * 8) = v;
    }
    __syncthreads();

    const int lane = tid & 63, wave = tid >> 6;
    const int wr = wave >> 1, wc = wave & 1;
    const int lrow = lane & 15, lk = lane >> 4;

    f32x4 acc[4][4];
    #pragma unroll
    for (int mi = 0; mi < 4; ++mi)
        #pragma unroll
        for (int ni = 0; ni < 4; ++ni) acc[mi][ni] = (f32x4){0.f, 0.f, 0.f, 0.f};

    #pragma unroll
    for (int kk = 0; kk < 4; ++kk) {
        s16x8 a[4], b[4];
        #pragma unroll
        for (int mi = 0; mi < 4; ++mi) {
            int row = wr * 64 + mi * 16 + lrow;
            int c16 = (lk + kk * 4) ^ (row & 7);
            a[mi] = *(const s16x8*)(As + row * 128 + c16 * 8);
        }
        #pragma unroll
        for (int ni = 0; ni < 4; ++ni) {
            int n = n0 + wc * 64 + ni * 16 + lrow;
            b[ni] = *(const s16x8*)(Bt + (size_t)n * 128 + kk * 32 + lk * 8);
        }
        #pragma unroll
        for (int mi = 0; mi < 4; ++mi)
            #pragma unroll
            for (int ni = 0; ni < 4; ++ni)
                acc[mi][ni] = __builtin_amdgcn_mfma_f32_16x16x32_bf16(
                    a[mi], b[ni], acc[mi][ni], 0, 0, 0);
    }

    if (OUT_BF16) {
        __syncthreads();               // done reading As; reuse as C staging
        ushort* Cl = As;
        #pragma unroll
        for (int mi = 0; mi < 4; ++mi)
            #pragma unroll
            for (int ni = 0; ni < 4; ++ni)
                #pragma unroll
                for (int r = 0; r < 4; ++r) {
                    int row = wr * 64 + mi * 16 + (lane >> 4) * 4 + r;
                    int col = wc * 64 + ni * 16 + (lane & 15);
                    float v = acc[mi][ni][r] + (bias ? bias[n0 + col] : 0.f);
                    Cl[row * 128 + (((col >> 3) ^ (row & 7)) << 3) + (col & 7)] = f2bf(v);
                }
        __syncthreads();
        ushort* C = (ushort*)Cv;
        #pragma unroll
        for (int p = 0; p < 8; ++p) {
            int c = p * 256 + tid;
            int row = c >> 4, c16 = c & 15;
            int gr = m0 + row;
            if (gr < M)
                *(int4*)(C + (size_t)gr * N + n0 + c16 * 8) =
                    *(const int4*)(As + row * 128 + (c16 ^ (row & 7)) * 8);
        }
    } else {
        float* C = (float*)Cv;
        #pragma unroll
        for (int mi = 0; mi < 4; ++mi)
            #pragma unroll
            for (int ni = 0; ni < 4; ++ni)
                #pragma unroll
                for (int r = 0; r < 4; ++r) {
                    int row = m0 + wr * 64 + mi * 16 + (lane >> 4) * 4 + r;
                    int col = n0 + wc * 64 + ni * 16 + (lane & 15);
                    if (row < M)
                        C[(size_t)row * N + col] =
                            acc[mi][ni][r] + (bias ? bias[col] : 0.f);
                }
    }
}

// ---------------------------------------------------------------------------
// Weight prep: transpose 128x128 fp32 mats -> bf16 [n][k] panels.
// 59 mats: 48 panel mats (2 layers x (9 PQ + 9 PV + 6 SL)),
//          6 Ws sums (2 layers x 3 dst groups), 5 final mats.
// ---------------------------------------------------------------------------
__global__ void prep_mats(
    const float* __restrict__ Wk, const float* __restrict__ Wq,
    const float* __restrict__ Wv, const float* __restrict__ Ws,
    const float* __restrict__ Wgt, const float* __restrict__ Wq1,
    const float* __restrict__ Wk2, const float* __restrict__ Wv2,
    const float* __restrict__ Wo,
    ushort* __restrict__ panels, ushort* __restrict__ wssum,
    ushort* __restrict__ finalw)
{
    const int m = blockIdx.x >> 6;
    const int e = (blockIdx.x & 63) * 256 + threadIdx.x;   // 0..16383
    const int nl = e >> 7, k = e & 127;
    const int dstlist[3][3] = {{0,3,6},{1,4,7},{2,5,-1}};
    const int srclist[3][3] = {{0,1,2},{3,4,5},{6,7,-1}};
    const int nkg[3] = {3,3,2}, nqg[3] = {3,3,2};
    const int gofs[3] = {0,1152,2304};

    if (m < 48) {
        int l = m / 24, r = m % 24;
        int g, slot;
        if (r < 9)       { g = 0; slot = r; }
        else if (r < 18) { g = 1; slot = r - 9; }
        else             { g = 2; slot = r - 18; }
        const float* src; int t;
        if (slot < nkg[g])               { t = dstlist[g][slot]; src = Wk; }
        else if (slot < nkg[g] + nqg[g]) { t = srclist[g][slot - nkg[g]]; src = Wq; }
        else                             { t = srclist[g][slot - nkg[g] - nqg[g]]; src = Wv; }
        src += (size_t)(l * 8 + t) * 16384;
        panels[((size_t)l * 3072 + gofs[g] + slot * 128 + nl) * 128 + k] =
            f2bf(src[k * 128 + nl]);
    } else if (m < 54) {
        int idx = m - 48, l = idx / 3, g = idx % 3;
        float s = 0.f;
        #pragma unroll
        for (int i = 0; i < 3; ++i) {
            int t = dstlist[g][i];
            if (t >= 0) s += Ws[(size_t)(l * 8 + t) * 16384 + k * 128 + nl];
        }
        wssum[(size_t)idx * 16384 + nl * 128 + k] = f2bf(s);
    } else {
        const float* fsrc[5] = {Wgt, Wq1, Wk2, Wv2, Wo};
        int idx = m - 54;
        finalw[(size_t)idx * 16384 + nl * 128 + k] = f2bf(fsrc[idx][k * 128 + nl]);
    }
}

__global__ void prep_bias(
    const float* __restrict__ bk, const float* __restrict__ bq,
    const float* __restrict__ bv, const float* __restrict__ bconv,
    float* __restrict__ bias_cat, float* __restrict__ bcsum)
{
    const int l = blockIdx.x / 3, g = blockIdx.x % 3;
    const int dstlist[3][3] = {{0,3,6},{1,4,7},{2,5,-1}};
    const int srclist[3][3] = {{0,1,2},{3,4,5},{6,7,-1}};
    const int nkg[3] = {3,3,2}, nqg[3] = {3,3,2};
    const int ncolg[3] = {1152,1152,768};
    const int gofs[3] = {0,1152,2304};
    for (int n = threadIdx.x; n < ncolg[g]; n += 256) {
        int slot = n >> 7, j = n & 127;
        const float* src; int t;
        if (slot < nkg[g])               { t = dstlist[g][slot]; src = bk; }
        else if (slot < nkg[g] + nqg[g]) { t = srclist[g][slot - nkg[g]]; src = bq; }
        else                             { t = srclist[g][slot - nkg[g] - nqg[g]]; src = bv; }
        bias_cat[l * 3072 + gofs[g] + n] = src[(l * 8 + t) * 128 + j];
    }
    if (threadIdx.x < 128) {
        float s = 0.f;
        #pragma unroll
        for (int i = 0; i < 3; ++i) {
            int t = dstlist[g][i];
            if (t >= 0) s += bconv[(l * 8 + t) * 128 + threadIdx.x];
        }
        bcsum[(l * 3 + g) * 128 + threadIdx.x] = s;
    }
}

// ---------------------------------------------------------------------------
// Edge kernel: 128 threads/edge; bf16 gathers; e_ = ea@We+be on the fly.
// ---------------------------------------------------------------------------
__global__ __launch_bounds__(256) void edge_kernel(
    const int* __restrict__ ei, const float* __restrict__ ea,
    const float* __restrict__ We, const float* __restrict__ be,
    const ushort* __restrict__ Yk, int ldk,
    const ushort* __restrict__ Yq, const ushort* __restrict__ Yv, int ldq,
    float* __restrict__ nd, int E)
{
    const int e = blockIdx.x * 2 + (threadIdx.x >> 7);
    if (e >= E) return;
    const int j = threadIdx.x & 127;
    const int si = ei[e];
    const int di = ei[E + e];

    float ej = be[j];
    #pragma unroll
    for (int r = 0; r < 16; ++r)
        ej += ea[(size_t)e * 16 + r] * We[r * 128 + j];

    float kv = bf2f(Yk[(size_t)di * ldk + j]);
    float qv = bf2f(Yq[(size_t)si * ldq + j]);
    float vv = bf2f(Yv[(size_t)si * ldq + j]);
    float g  = 1.f / (1.f + __expf(-(kv + qv + ej)));
    atomicAdd(&nd[(size_t)di * 128 + j], g * vv);
}

// ---------------------------------------------------------------------------
// Elementwise helpers
// ---------------------------------------------------------------------------
__global__ void f2b_kernel(const float* __restrict__ a, ushort* __restrict__ o, int n)
{
    int i = (blockIdx.x * 256 + threadIdx.x) * 4;
    if (i < n) {
        float4 v = *(const float4*)(a + i);
        ushort4 u; u.x = f2bf(v.x); u.y = f2bf(v.y); u.z = f2bf(v.z); u.w = f2bf(v.w);
        *(ushort4*)(o + i) = u;
    }
}
__global__ void relu_b_kernel(const float* __restrict__ a, ushort* __restrict__ o, int n)
{
    int i = (blockIdx.x * 256 + threadIdx.x) * 4;
    if (i < n) {
        float4 v = *(const float4*)(a + i);
        ushort4 u;
        u.x = f2bf(fmaxf(v.x, 0.f)); u.y = f2bf(fmaxf(v.y, 0.f));
        u.z = f2bf(fmaxf(v.z, 0.f)); u.w = f2bf(fmaxf(v.w, 0.f));
        *(ushort4*)(o + i) = u;
    }
}
__global__ void b2f_kernel(const ushort* __restrict__ a, float* __restrict__ o, int n)
{
    int i = blockIdx.x * 256 + threadIdx.x;
    if (i < n) o[i] = bf2f(a[i]);
}

// ---------------------------------------------------------------------------
// Global pooling over gf (bf16): two-stage mean+max
// ---------------------------------------------------------------------------
__global__ void pool1(const ushort* __restrict__ gf, float* __restrict__ pbuf)
{
    const int b = blockIdx.x >> 4, c = blockIdx.x & 15;
    const int j = threadIdx.x;   // 128
    float s = 0.f, m = -INFINITY;
    const ushort* pq = gf + (size_t)(b * 1024 + c * 64) * 128;
    for (int i = 0; i < 64; ++i) { float v = bf2f(pq[i * 128 + j]); s += v; m = fmaxf(m, v); }
    const ushort* pv = gf + (size_t)(N_PQ + b * 256 + c * 16) * 128;
    for (int i = 0; i < 16; ++i) { float v = bf2f(pv[i * 128 + j]); s += v; m = fmaxf(m, v); }
    if (c == 0) { float v = bf2f(gf[(size_t)(N_PQ + N_PV + b) * 128 + j]); s += v; m = fmaxf(m, v); }
    pbuf[(size_t)blockIdx.x * 256 + j] = s;
    pbuf[(size_t)blockIdx.x * 256 + 128 + j] = m;
}
__global__ void pool2(const float* __restrict__ pbuf, float* __restrict__ gnode)
{
    const int b = blockIdx.x, j = threadIdx.x;
    float s = 0.f, m = -INFINITY;
    for (int c = 0; c < 16; ++c) {
        s += pbuf[(size_t)(b * 16 + c) * 256 + j];
        m = fmaxf(m, pbuf[(size_t)(b * 16 + c) * 256 + 128 + j]);
    }
    gnode[(size_t)(b * 2) * 128 + j]     = s * (1.f / 1281.f);
    gnode[(size_t)(b * 2 + 1) * 128 + j] = m;
}

// ---------------------------------------------------------------------------
// Cross-attention (2 keys), q in bf16, out bf16
// ---------------------------------------------------------------------------
__global__ __launch_bounds__(256) void attn_kernel(
    const ushort* __restrict__ q, const float* __restrict__ k2,
    const float* __restrict__ v2, ushort* __restrict__ ao, int shift, int Ntot)
{
    const int n = blockIdx.x * 2 + (threadIdx.x >> 7);
    if (n >= Ntot) return;
    const int j = threadIdx.x & 127;
    const int b = n >> shift;
    const int h16 = j & ~15;

    const ushort* qn = q + (size_t)n * 128 + h16;
    const float* k0 = k2 + (size_t)(b * 2) * 128 + h16;
    const float* k1 = k2 + (size_t)(b * 2 + 1) * 128 + h16;
    float s0 = 0.f, s1 = 0.f;
    #pragma unroll
    for (int d = 0; d < 16; ++d) {
        float qq = bf2f(qn[d]); s0 += qq * k0[d]; s1 += qq * k1[d];
    }
    s0 *= 0.25f; s1 *= 0.25f;
    float m  = fmaxf(s0, s1);
    float a0 = __expf(s0 - m), a1 = __expf(s1 - m);
    float inv = 1.f / (a0 + a1);
    ao[(size_t)n * 128 + j] = f2bf(
        (a0 * v2[(size_t)(b * 2) * 128 + j] + a1 * v2[(size_t)(b * 2 + 1) * 128 + j]) * inv);
}

// ---------------------------------------------------------------------------
// LayerNorm: out = LN(bf16(x) + ca) * g + b ; one wave per node
// ---------------------------------------------------------------------------
__global__ __launch_bounds__(256) void ln_kernel(
    const ushort* __restrict__ x, const float* __restrict__ ca,
    const float* __restrict__ g, const float* __restrict__ bb,
    float* __restrict__ out, int N)
{
    const int n = blockIdx.x * 4 + (threadIdx.x >> 6);
    if (n >= N) return;
    const int l = threadIdx.x & 63;
    const size_t base = (size_t)n * 128;
    float h0 = bf2f(x[base + l * 2])     + ca[base + l * 2];
    float h1 = bf2f(x[base + l * 2 + 1]) + ca[base + l * 2 + 1];
    float s  = h0 + h1;
    float ss = h0 * h0 + h1 * h1;
    #pragma unroll
    for (int o = 32; o; o >>= 1) { s += __shfl_xor(s, o); ss += __shfl_xor(ss, o); }
    float mu  = s * (1.f / 128.f);
    float var = ss * (1.f / 128.f) - mu * mu;
    float rs  = rsqrtf(var + 1e-5f);
    out[base + l * 2]     = (h0 - mu) * rs * g[l * 2]     + bb[l * 2];
    out[base + l * 2 + 1] = (h1 - mu) * rs * g[l * 2 + 1] + bb[l * 2 + 1];
}

// ---------------------------------------------------------------------------
// Host orchestration
// ---------------------------------------------------------------------------
extern "C" void kernel_launch(void* const* d_in, const int* in_sizes, int n_in,
                              void* d_out, int out_size, void* d_ws, size_t ws_size,
                              hipStream_t stream)
{
    const float* xin[3] = {(const float*)d_in[0], (const float*)d_in[1], (const float*)d_in[2]};
    const int NNs[3] = {N_PQ, N_PV, N_SL};
    const int ncol[3] = {1152, 1152, 768};
    const int gofs[3] = {0, 1152, 2304};

    const int*   ei[8];
    const float* ea[8];
    int          Ecnt[8];
    for (int t = 0; t < 8; ++t) {
        ei[t]   = (const int*)d_in[3 + 2 * t];
        ea[t]   = (const float*)d_in[4 + 2 * t];
        Ecnt[t] = in_sizes[3 + 2 * t] / 2;
    }
    const float* Wk    = (const float*)d_in[19];
    const float* bk    = (const float*)d_in[20];
    const float* Wq    = (const float*)d_in[21];
    const float* bq    = (const float*)d_in[22];
    const float* Wv    = (const float*)d_in[23];
    const float* bv    = (const float*)d_in[24];
    const float* Ws    = (const float*)d_in[25];
    const float* bconv = (const float*)d_in[26];
    const float* We    = (const float*)d_in[27];
    const float* be    = (const float*)d_in[28];
    const float* Wgt   = (const float*)d_in[29];
    const float* bgt   = (const float*)d_in[30];
    const float* Wq1   = (const float*)d_in[31];
    const float* Wk2   = (const float*)d_in[32];
    const float* Wv2   = (const float*)d_in[33];
    const float* Wo    = (const float*)d_in[34];
    const float* bo    = (const float*)d_in[35];
    const float* ln_g  = (const float*)d_in[36];
    const float* ln_b  = (const float*)d_in[37];

    // ---- workspace carve-up ----
    char* w = (char*)d_ws;
    ushort* Y[3];
    Y[0] = (ushort*)w; w += (size_t)N_PQ * 1152 * 2;
    Y[1] = (ushort*)w; w += (size_t)N_PV * 1152 * 2;
    Y[2] = (ushort*)w; w += (size_t)N_SL * 768 * 2;
    ushort* xb[3];
    xb[0] = (ushort*)w; w += (size_t)N_PQ * 128 * 2;
    xb[1] = (ushort*)w; w += (size_t)N_PV * 128 * 2;
    xb[2] = (ushort*)w; w += (size_t)N_SL * 128 * 2;
    ushort* panels = (ushort*)w; w += (size_t)786432 * 2;
    ushort* wssum  = (ushort*)w; w += (size_t)98304 * 2;
    ushort* finalw = (ushort*)w; w += (size_t)81920 * 2;
    float* bias_cat = (float*)w; w += 6144 * 4;
    float* bcsum    = (float*)w; w += 768 * 4;
    float* gnode    = (float*)w; w += 16384 * 4;
    ushort* gnodeb  = (ushort*)w; w += 16384 * 2;
    float* k2       = (float*)w; w += 16384 * 4;
    float* v2       = (float*)w; w += 16384 * 4;
    float* pbuf     = (float*)w; w += 1024 * 256 * 4;
    // overlays into Y[0] (layer buffers dead at those times):
    ushort* gf   = Y[0];                                   // 81984x128 bf16 (start)
    ushort* qb   = Y[0];                                   // final stage
    ushort* ao   = (ushort*)((char*)Y[0] + (size_t)N_PQ * 128 * 2);
    float*  cbuf = (float*)((char*)Y[0] + (size_t)N_PQ * 128 * 4);
    // nw accumulators live in d_out (fp32), fully written before reads
    float* outp = (float*)d_out;
    float* nw[3] = {outp, outp + (size_t)N_PQ * 128, outp + (size_t)(N_PQ + N_PV) * 128};

    const ushort* Wgt_t = finalw;
    const ushort* Wq1_t = finalw + 16384;
    const ushort* Wk2_t = finalw + 32768;
    const ushort* Wv2_t = finalw + 49152;
    const ushort* Wo_t  = finalw + 65536;

    auto gemm_b = [&](const ushort* A, const ushort* Bt, const float* bias,
                      ushort* C, int M, int N) {
        gemm_mfma<1><<<dim3((M + 127) / 128, N / 128), 256, 0, stream>>>(A, Bt, bias, C, M, N);
    };
    auto gemm_f = [&](const ushort* A, const ushort* Bt, const float* bias,
                      float* C, int M, int N) {
        gemm_mfma<0><<<dim3((M + 127) / 128, N / 128), 256, 0, stream>>>(A, Bt, bias, C, M, N);
    };

    // 1) weight prep + input converts
    prep_mats<<<59 * 64, 256, 0, stream>>>(Wk, Wq, Wv, Ws, Wgt, Wq1, Wk2, Wv2, Wo,
                                           panels, wssum, finalw);
    prep_bias<<<6, 256, 0, stream>>>(bk, bq, bv, bconv, bias_cat, bcsum);
    for (int g = 0; g < 3; ++g) {
        int n = NNs[g] * 128;
        f2b_kernel<<<dim3((n / 4 + 255) / 256), 256, 0, stream>>>(xin[g], xb[g], n);
    }

    // 2) global features + pooling + k2/v2
    gemm_b(xb[0], Wgt_t, bgt, gf, N_PQ, 128);
    gemm_b(xb[1], Wgt_t, bgt, gf + (size_t)N_PQ * 128, N_PV, 128);
    gemm_b(xb[2], Wgt_t, bgt, gf + (size_t)(N_PQ + N_PV) * 128, N_SL, 128);
    pool1<<<1024, 128, 0, stream>>>(gf, pbuf);
    pool2<<<64, 128, 0, stream>>>(pbuf, gnode);
    f2b_kernel<<<dim3(16384 / 4 / 256), 256, 0, stream>>>(gnode, gnodeb, 16384);
    gemm_f(gnodeb, Wk2_t, nullptr, k2, 128, 128);
    gemm_f(gnodeb, Wv2_t, nullptr, v2, 128, 128);

    // 3) two HeteroConv layers
    const int srcs[8] = {0, 0, 0, 1, 1, 1, 2, 2};
    const int dsts[8] = {0, 1, 2, 0, 1, 2, 0, 1};
    const int kpos[8] = {0, 0, 0, 1, 1, 1, 2, 2};
    const int qpos[8] = {0, 1, 2, 0, 1, 2, 0, 1};
    const int nkg[3] = {3, 3, 2}, nqg[3] = {3, 3, 2};

    for (int l = 0; l < 2; ++l) {
        for (int g = 0; g < 3; ++g)
            gemm_b(xb[g], panels + ((size_t)l * 3072 + gofs[g]) * 128,
                   bias_cat + l * 3072 + gofs[g], Y[g], NNs[g], ncol[g]);
        for (int g = 0; g < 3; ++g)
            gemm_f(xb[g], wssum + (size_t)(l * 3 + g) * 16384,
                   bcsum + (l * 3 + g) * 128, nw[g], NNs[g], 128);
        for (int t = 0; t < 8; ++t) {
            int s = srcs[t], d = dsts[t], off = l * 8 + t;
            const ushort* Yk = Y[d] + kpos[t] * 128;
            const ushort* Yq = Y[s] + (nkg[s] + qpos[t]) * 128;
            const ushort* Yv = Y[s] + (nkg[s] + nqg[s] + qpos[t]) * 128;
            edge_kernel<<<dim3((Ecnt[t] + 1) / 2), 256, 0, stream>>>(
                ei[t], ea[t], We + (size_t)off * 2048, be + (size_t)off * 128,
                Yk, ncol[d], Yq, Yv, ncol[s], nw[d], Ecnt[t]);
        }
        for (int g = 0; g < 3; ++g) {
            int n = NNs[g] * 128;
            relu_b_kernel<<<dim3((n / 4 + 255) / 256), 256, 0, stream>>>(nw[g], xb[g], n);
        }
    }

    // 4) cross-attention + residual + LayerNorm
    // PQ
    gemm_b(xb[0], Wq1_t, nullptr, qb, N_PQ, 128);
    attn_kernel<<<dim3(N_PQ / 2), 256, 0, stream>>>(qb, k2, v2, ao, 10, N_PQ);
    gemm_f(ao, Wo_t, bo, cbuf, N_PQ, 128);
    ln_kernel<<<dim3(N_PQ / 4), 256, 0, stream>>>(xb[0], cbuf, ln_g, ln_b, outp, N_PQ);
    // PV
    gemm_b(xb[1], Wq1_t, nullptr, qb, N_PV, 128);
    attn_kernel<<<dim3(N_PV / 2), 256, 0, stream>>>(qb, k2, v2, ao, 8, N_PV);
    gemm_f(ao, Wo_t, bo, cbuf, N_PV, 128);
    ln_kernel<<<dim3(N_PV / 4), 256, 0, stream>>>(xb[1], cbuf, ln_g, ln_b,
                                                  outp + (size_t)N_PQ * 128, N_PV);
    // Slack: bf16 state -> fp32 out
    b2f_kernel<<<dim3((N_SL * 128 + 255) / 256), 256, 0, stream>>>(
        xb[2], outp + (size_t)(N_PQ + N_PV) * 128, N_SL * 128);
}

// Round 3
// 1104.279 us; speedup vs baseline: 2.7047x; 1.3123x over previous
//
#include <hip/hip_runtime.h>
#include <hip/hip_bf16.h>
#include <math.h>

#define N_PQ 65536
#define N_PV 16384
#define N_SL 64

typedef __attribute__((ext_vector_type(8))) short s16x8;
typedef __attribute__((ext_vector_type(4))) float f32x4;

__device__ __forceinline__ ushort f2bf(float f) {
    union { float f; unsigned u; } x; x.f = f;
    unsigned r = x.u + 0x7fff + ((x.u >> 16) & 1);
    return (ushort)(r >> 16);
}
__device__ __forceinline__ float bf2f(ushort u) {
    union { unsigned u; float f; } x; x.u = ((unsigned)u) << 16;
    return x.f;
}

// ---------------------------------------------------------------------------
// MFMA GEMM: C[M,N] = A[M,128](bf16) @ Bt[N,128](bf16, n-major) + bias
// ---------------------------------------------------------------------------
template<int OUT_BF16>
__global__ __launch_bounds__(256) void gemm_mfma(
    const ushort* __restrict__ A, const ushort* __restrict__ Bt,
    const float* __restrict__ bias, void* __restrict__ Cv, int M, int N)
{
    __shared__ ushort As[128 * 128];
    const int tid = threadIdx.x;
    const int m0 = blockIdx.x * 128;
    const int n0 = blockIdx.y * 128;

    #pragma unroll
    for (int p = 0; p < 8; ++p) {
        int c = p * 256 + tid;
        int row = c >> 4, c16 = c & 15;
        int gr = m0 + row;
        int4 v = make_int4(0, 0, 0, 0);
        if (gr < M) v = *(const int4*)(A + (size_t)gr * 128 + c16 * 8);
        *(int4*)(As + row * 128 + (c16 ^ (row & 7)) * 8) = v;
    }
    __syncthreads();

    const int lane = tid & 63, wave = tid >> 6;
    const int wr = wave >> 1, wc = wave & 1;
    const int lrow = lane & 15, lk = lane >> 4;

    f32x4 acc[4][4];
    #pragma unroll
    for (int mi = 0; mi < 4; ++mi)
        #pragma unroll
        for (int ni = 0; ni < 4; ++ni) acc[mi][ni] = (f32x4){0.f, 0.f, 0.f, 0.f};

    #pragma unroll
    for (int kk = 0; kk < 4; ++kk) {
        s16x8 a[4], b[4];
        #pragma unroll
        for (int mi = 0; mi < 4; ++mi) {
            int row = wr * 64 + mi * 16 + lrow;
            int c16 = (lk + kk * 4) ^ (row & 7);
            a[mi] = *(const s16x8*)(As + row * 128 + c16 * 8);
        }
        #pragma unroll
        for (int ni = 0; ni < 4; ++ni) {
            int n = n0 + wc * 64 + ni * 16 + lrow;
            b[ni] = *(const s16x8*)(Bt + (size_t)n * 128 + kk * 32 + lk * 8);
        }
        #pragma unroll
        for (int mi = 0; mi < 4; ++mi)
            #pragma unroll
            for (int ni = 0; ni < 4; ++ni)
                acc[mi][ni] = __builtin_amdgcn_mfma_f32_16x16x32_bf16(
                    a[mi], b[ni], acc[mi][ni], 0, 0, 0);
    }

    if (OUT_BF16) {
        __syncthreads();
        ushort* Cl = As;
        #pragma unroll
        for (int mi = 0; mi < 4; ++mi)
            #pragma unroll
            for (int ni = 0; ni < 4; ++ni)
                #pragma unroll
                for (int r = 0; r < 4; ++r) {
                    int row = wr * 64 + mi * 16 + (lane >> 4) * 4 + r;
                    int col = wc * 64 + ni * 16 + (lane & 15);
                    float v = acc[mi][ni][r] + (bias ? bias[n0 + col] : 0.f);
                    Cl[row * 128 + (((col >> 3) ^ (row & 7)) << 3) + (col & 7)] = f2bf(v);
                }
        __syncthreads();
        ushort* C = (ushort*)Cv;
        #pragma unroll
        for (int p = 0; p < 8; ++p) {
            int c = p * 256 + tid;
            int row = c >> 4, c16 = c & 15;
            int gr = m0 + row;
            if (gr < M)
                *(int4*)(C + (size_t)gr * N + n0 + c16 * 8) =
                    *(const int4*)(As + row * 128 + (c16 ^ (row & 7)) * 8);
        }
    } else {
        float* C = (float*)Cv;
        #pragma unroll
        for (int mi = 0; mi < 4; ++mi)
            #pragma unroll
            for (int ni = 0; ni < 4; ++ni)
                #pragma unroll
                for (int r = 0; r < 4; ++r) {
                    int row = m0 + wr * 64 + mi * 16 + (lane >> 4) * 4 + r;
                    int col = n0 + wc * 64 + ni * 16 + (lane & 15);
                    if (row < M)
                        C[(size_t)row * N + col] =
                            acc[mi][ni][r] + (bias ? bias[col] : 0.f);
                }
    }
}

// ---------------------------------------------------------------------------
// Weight prep (unchanged from round 2)
// ---------------------------------------------------------------------------
__global__ void prep_mats(
    const float* __restrict__ Wk, const float* __restrict__ Wq,
    const float* __restrict__ Wv, const float* __restrict__ Ws,
    const float* __restrict__ Wgt, const float* __restrict__ Wq1,
    const float* __restrict__ Wk2, const float* __restrict__ Wv2,
    const float* __restrict__ Wo,
    ushort* __restrict__ panels, ushort* __restrict__ wssum,
    ushort* __restrict__ finalw)
{
    const int m = blockIdx.x >> 6;
    const int e = (blockIdx.x & 63) * 256 + threadIdx.x;
    const int nl = e >> 7, k = e & 127;
    const int dstlist[3][3] = {{0,3,6},{1,4,7},{2,5,-1}};
    const int srclist[3][3] = {{0,1,2},{3,4,5},{6,7,-1}};
    const int nkg[3] = {3,3,2}, nqg[3] = {3,3,2};
    const int gofs[3] = {0,1152,2304};

    if (m < 48) {
        int l = m / 24, r = m % 24;
        int g, slot;
        if (r < 9)       { g = 0; slot = r; }
        else if (r < 18) { g = 1; slot = r - 9; }
        else             { g = 2; slot = r - 18; }
        const float* src; int t;
        if (slot < nkg[g])               { t = dstlist[g][slot]; src = Wk; }
        else if (slot < nkg[g] + nqg[g]) { t = srclist[g][slot - nkg[g]]; src = Wq; }
        else                             { t = srclist[g][slot - nkg[g] - nqg[g]]; src = Wv; }
        src += (size_t)(l * 8 + t) * 16384;
        panels[((size_t)l * 3072 + gofs[g] + slot * 128 + nl) * 128 + k] =
            f2bf(src[k * 128 + nl]);
    } else if (m < 54) {
        int idx = m - 48, l = idx / 3, g = idx % 3;
        float s = 0.f;
        #pragma unroll
        for (int i = 0; i < 3; ++i) {
            int t = dstlist[g][i];
            if (t >= 0) s += Ws[(size_t)(l * 8 + t) * 16384 + k * 128 + nl];
        }
        wssum[(size_t)idx * 16384 + nl * 128 + k] = f2bf(s);
    } else {
        const float* fsrc[5] = {Wgt, Wq1, Wk2, Wv2, Wo};
        int idx = m - 54;
        finalw[(size_t)idx * 16384 + nl * 128 + k] = f2bf(fsrc[idx][k * 128 + nl]);
    }
}

__global__ void prep_bias(
    const float* __restrict__ bk, const float* __restrict__ bq,
    const float* __restrict__ bv, const float* __restrict__ bconv,
    float* __restrict__ bias_cat, float* __restrict__ bcsum)
{
    const int l = blockIdx.x / 3, g = blockIdx.x % 3;
    const int dstlist[3][3] = {{0,3,6},{1,4,7},{2,5,-1}};
    const int srclist[3][3] = {{0,1,2},{3,4,5},{6,7,-1}};
    const int nkg[3] = {3,3,2}, nqg[3] = {3,3,2};
    const int ncolg[3] = {1152,1152,768};
    const int gofs[3] = {0,1152,2304};
    for (int n = threadIdx.x; n < ncolg[g]; n += 256) {
        int slot = n >> 7, j = n & 127;
        const float* src; int t;
        if (slot < nkg[g])               { t = dstlist[g][slot]; src = bk; }
        else if (slot < nkg[g] + nqg[g]) { t = srclist[g][slot - nkg[g]]; src = bq; }
        else                             { t = srclist[g][slot - nkg[g] - nqg[g]]; src = bv; }
        bias_cat[l * 3072 + gofs[g] + n] = src[(l * 8 + t) * 128 + j];
    }
    if (threadIdx.x < 128) {
        float s = 0.f;
        #pragma unroll
        for (int i = 0; i < 3; ++i) {
            int t = dstlist[g][i];
            if (t >= 0) s += bconv[(l * 8 + t) * 128 + threadIdx.x];
        }
        bcsum[(l * 3 + g) * 128 + threadIdx.x] = s;
    }
}

// ---------------------------------------------------------------------------
// CSR build: histogram -> scan -> scatter  (6 types: dst in {PQ, PV})
// ---------------------------------------------------------------------------
struct HArgs {
    const int* ei[6];
    int E[6];
    int base[6];
    int cum[7];
};

__global__ void hist_kernel(HArgs A, int* __restrict__ bins)
{
    int g = blockIdx.x * 256 + threadIdx.x;
    if (g >= A.cum[6]) return;
    int t = 0;
    #pragma unroll
    for (int i = 0; i < 5; ++i) t += (g >= A.cum[i + 1]);
    int e = g - A.cum[t];
    int dst = A.ei[t][A.E[t] + e];
    atomicAdd(&bins[A.base[t] + dst], 1);
}

__global__ __launch_bounds__(1024) void scan_kernel(
    const int* __restrict__ bins, int* __restrict__ offs)
{
    __shared__ int sums[1024];
    const int tid = threadIdx.x;
    const int b0 = tid * 256;
    int s = 0;
    for (int i = 0; i < 256; ++i) s += bins[b0 + i];
    sums[tid] = s;
    __syncthreads();
    for (int off = 1; off < 1024; off <<= 1) {
        int v = (tid >= off) ? sums[tid - off] : 0;
        __syncthreads();
        if (tid >= off) sums[tid] += v;
        __syncthreads();
    }
    int run = (tid > 0) ? sums[tid - 1] : 0;
    for (int i = 0; i < 256; ++i) { offs[b0 + i] = run; run += bins[b0 + i]; }
}

__global__ void scatter_kernel(HArgs A, int* __restrict__ cursor,
                               int* __restrict__ lsrc, int* __restrict__ leid)
{
    int g = blockIdx.x * 256 + threadIdx.x;
    if (g >= A.cum[6]) return;
    int t = 0;
    #pragma unroll
    for (int i = 0; i < 5; ++i) t += (g >= A.cum[i + 1]);
    int e = g - A.cum[t];
    int src = A.ei[t][e];
    int dst = A.ei[t][A.E[t] + e];
    int pos = atomicAdd(&cursor[A.base[t] + dst], 1);
    lsrc[pos] = src;
    leid[pos] = e;
}

// ---------------------------------------------------------------------------
// CSR gather: one wave per dst node, 2 features per lane, 3 incoming types.
// acc init from nw (Ws GEMM), fused ReLU + bf16 store. No atomics.
// ---------------------------------------------------------------------------
struct GTA {
    int base, kcol, lds, qcol, vcol;
    const ushort* Ys;
    const float* ea;
    const float* We;
    const float* be;
};
struct GArgs {
    GTA t[3];
    const int* offs;
    const int* lsrc;
    const int* leid;
    const float* nwg;
    ushort* xbg;
    const ushort* Yg;
    int ldg;
};

__global__ __launch_bounds__(256) void gather_kernel(GArgs A)
{
    const int wave = threadIdx.x >> 6, lane = threadIdx.x & 63;
    const int d = blockIdx.x * 4 + wave;
    const int j0 = lane * 2;

    float2 nw2 = *(const float2*)(A.nwg + (size_t)d * 128 + j0);
    float a0 = nw2.x, a1 = nw2.y;

    #pragma unroll
    for (int i = 0; i < 3; ++i) {
        const GTA T = A.t[i];
        int start = __builtin_amdgcn_readfirstlane(A.offs[T.base + d]);
        int end   = __builtin_amdgcn_readfirstlane(A.offs[T.base + d + 1]);
        if (start == end) continue;

        ushort2 kk = *(const ushort2*)(A.Yg + (size_t)d * A.ldg + T.kcol + j0);
        float k0 = bf2f(kk.x), k1 = bf2f(kk.y);

        float we0[16], we1[16];
        #pragma unroll
        for (int r = 0; r < 16; ++r) {
            float2 w2 = *(const float2*)(T.We + r * 128 + j0);
            we0[r] = w2.x; we1[r] = w2.y;
        }
        float2 be2 = *(const float2*)(T.be + j0);

        int si  = __builtin_amdgcn_readfirstlane(A.lsrc[start]);
        int eid = __builtin_amdgcn_readfirstlane(A.leid[start]);
        for (int e = start; e < end; ++e) {
            int si_c = si, eid_c = eid;
            if (e + 1 < end) {
                si  = __builtin_amdgcn_readfirstlane(A.lsrc[e + 1]);
                eid = __builtin_amdgcn_readfirstlane(A.leid[e + 1]);
            }
            const ushort* sp = T.Ys + (size_t)si_c * T.lds + j0;
            ushort2 q2 = *(const ushort2*)(sp + T.qcol);
            ushort2 v2 = *(const ushort2*)(sp + T.vcol);
            const float* eap = T.ea + (size_t)eid_c * 16;
            float e0 = be2.x, e1 = be2.y;
            #pragma unroll
            for (int r = 0; r < 16; ++r) {
                float er = eap[r];
                e0 += er * we0[r];
                e1 += er * we1[r];
            }
            float g0 = 1.f / (1.f + __expf(-(k0 + bf2f(q2.x) + e0)));
            float g1 = 1.f / (1.f + __expf(-(k1 + bf2f(q2.y) + e1)));
            a0 += g0 * bf2f(v2.x);
            a1 += g1 * bf2f(v2.y);
        }
    }
    ushort2 o; o.x = f2bf(fmaxf(a0, 0.f)); o.y = f2bf(fmaxf(a1, 0.f));
    *(ushort2*)(A.xbg + (size_t)d * 128 + j0) = o;
}

// ---------------------------------------------------------------------------
// Atomic edge kernel (kept for the tiny Slack-destination types 2 & 5)
// ---------------------------------------------------------------------------
__global__ __launch_bounds__(256) void edge_kernel(
    const int* __restrict__ ei, const float* __restrict__ ea,
    const float* __restrict__ We, const float* __restrict__ be,
    const ushort* __restrict__ Yk, int ldk,
    const ushort* __restrict__ Yq, const ushort* __restrict__ Yv, int ldq,
    float* __restrict__ nd, int E)
{
    const int e = blockIdx.x * 2 + (threadIdx.x >> 7);
    if (e >= E) return;
    const int j = threadIdx.x & 127;
    const int si = ei[e];
    const int di = ei[E + e];

    float ej = be[j];
    #pragma unroll
    for (int r = 0; r < 16; ++r)
        ej += ea[(size_t)e * 16 + r] * We[r * 128 + j];

    float kv = bf2f(Yk[(size_t)di * ldk + j]);
    float qv = bf2f(Yq[(size_t)si * ldq + j]);
    float vv = bf2f(Yv[(size_t)si * ldq + j]);
    float g  = 1.f / (1.f + __expf(-(kv + qv + ej)));
    atomicAdd(&nd[(size_t)di * 128 + j], g * vv);
}

// ---------------------------------------------------------------------------
// Elementwise helpers
// ---------------------------------------------------------------------------
__global__ void f2b_kernel(const float* __restrict__ a, ushort* __restrict__ o, int n)
{
    int i = (blockIdx.x * 256 + threadIdx.x) * 4;
    if (i < n) {
        float4 v = *(const float4*)(a + i);
        ushort4 u; u.x = f2bf(v.x); u.y = f2bf(v.y); u.z = f2bf(v.z); u.w = f2bf(v.w);
        *(ushort4*)(o + i) = u;
    }
}
__global__ void relu_b_kernel(const float* __restrict__ a, ushort* __restrict__ o, int n)
{
    int i = (blockIdx.x * 256 + threadIdx.x) * 4;
    if (i < n) {
        float4 v = *(const float4*)(a + i);
        ushort4 u;
        u.x = f2bf(fmaxf(v.x, 0.f)); u.y = f2bf(fmaxf(v.y, 0.f));
        u.z = f2bf(fmaxf(v.z, 0.f)); u.w = f2bf(fmaxf(v.w, 0.f));
        *(ushort4*)(o + i) = u;
    }
}
__global__ void b2f_kernel(const ushort* __restrict__ a, float* __restrict__ o, int n)
{
    int i = blockIdx.x * 256 + threadIdx.x;
    if (i < n) o[i] = bf2f(a[i]);
}

// ---------------------------------------------------------------------------
// Global pooling over gf (bf16): two-stage mean+max
// ---------------------------------------------------------------------------
__global__ void pool1(const ushort* __restrict__ gf, float* __restrict__ pbuf)
{
    const int b = blockIdx.x >> 4, c = blockIdx.x & 15;
    const int j = threadIdx.x;
    float s = 0.f, m = -INFINITY;
    const ushort* pq = gf + (size_t)(b * 1024 + c * 64) * 128;
    for (int i = 0; i < 64; ++i) { float v = bf2f(pq[i * 128 + j]); s += v; m = fmaxf(m, v); }
    const ushort* pv = gf + (size_t)(N_PQ + b * 256 + c * 16) * 128;
    for (int i = 0; i < 16; ++i) { float v = bf2f(pv[i * 128 + j]); s += v; m = fmaxf(m, v); }
    if (c == 0) { float v = bf2f(gf[(size_t)(N_PQ + N_PV + b) * 128 + j]); s += v; m = fmaxf(m, v); }
    pbuf[(size_t)blockIdx.x * 256 + j] = s;
    pbuf[(size_t)blockIdx.x * 256 + 128 + j] = m;
}
__global__ void pool2(const float* __restrict__ pbuf, float* __restrict__ gnode)
{
    const int b = blockIdx.x, j = threadIdx.x;
    float s = 0.f, m = -INFINITY;
    for (int c = 0; c < 16; ++c) {
        s += pbuf[(size_t)(b * 16 + c) * 256 + j];
        m = fmaxf(m, pbuf[(size_t)(b * 16 + c) * 256 + 128 + j]);
    }
    gnode[(size_t)(b * 2) * 128 + j]     = s * (1.f / 1281.f);
    gnode[(size_t)(b * 2 + 1) * 128 + j] = m;
}

// ---------------------------------------------------------------------------
// Cross-attention (2 keys)
// ---------------------------------------------------------------------------
__global__ __launch_bounds__(256) void attn_kernel(
    const ushort* __restrict__ q, const float* __restrict__ k2,
    const float* __restrict__ v2, ushort* __restrict__ ao, int shift, int Ntot)
{
    const int n = blockIdx.x * 2 + (threadIdx.x >> 7);
    if (n >= Ntot) return;
    const int j = threadIdx.x & 127;
    const int b = n >> shift;
    const int h16 = j & ~15;

    const ushort* qn = q + (size_t)n * 128 + h16;
    const float* k0 = k2 + (size_t)(b * 2) * 128 + h16;
    const float* k1 = k2 + (size_t)(b * 2 + 1) * 128 + h16;
    float s0 = 0.f, s1 = 0.f;
    #pragma unroll
    for (int d = 0; d < 16; ++d) {
        float qq = bf2f(qn[d]); s0 += qq * k0[d]; s1 += qq * k1[d];
    }
    s0 *= 0.25f; s1 *= 0.25f;
    float m  = fmaxf(s0, s1);
    float a0 = __expf(s0 - m), a1 = __expf(s1 - m);
    float inv = 1.f / (a0 + a1);
    ao[(size_t)n * 128 + j] = f2bf(
        (a0 * v2[(size_t)(b * 2) * 128 + j] + a1 * v2[(size_t)(b * 2 + 1) * 128 + j]) * inv);
}

// ---------------------------------------------------------------------------
// LayerNorm
// ---------------------------------------------------------------------------
__global__ __launch_bounds__(256) void ln_kernel(
    const ushort* __restrict__ x, const float* __restrict__ ca,
    const float* __restrict__ g, const float* __restrict__ bb,
    float* __restrict__ out, int N)
{
    const int n = blockIdx.x * 4 + (threadIdx.x >> 6);
    if (n >= N) return;
    const int l = threadIdx.x & 63;
    const size_t base = (size_t)n * 128;
    float h0 = bf2f(x[base + l * 2])     + ca[base + l * 2];
    float h1 = bf2f(x[base + l * 2 + 1]) + ca[base + l * 2 + 1];
    float s  = h0 + h1;
    float ss = h0 * h0 + h1 * h1;
    #pragma unroll
    for (int o = 32; o; o >>= 1) { s += __shfl_xor(s, o); ss += __shfl_xor(ss, o); }
    float mu  = s * (1.f / 128.f);
    float var = ss * (1.f / 128.f) - mu * mu;
    float rs  = rsqrtf(var + 1e-5f);
    out[base + l * 2]     = (h0 - mu) * rs * g[l * 2]     + bb[l * 2];
    out[base + l * 2 + 1] = (h1 - mu) * rs * g[l * 2 + 1] + bb[l * 2 + 1];
}

// ---------------------------------------------------------------------------
// Host orchestration
// ---------------------------------------------------------------------------
extern "C" void kernel_launch(void* const* d_in, const int* in_sizes, int n_in,
                              void* d_out, int out_size, void* d_ws, size_t ws_size,
                              hipStream_t stream)
{
    const float* xin[3] = {(const float*)d_in[0], (const float*)d_in[1], (const float*)d_in[2]};
    const int NNs[3] = {N_PQ, N_PV, N_SL};
    const int ncol[3] = {1152, 1152, 768};
    const int gofs[3] = {0, 1152, 2304};

    const int*   ei[8];
    const float* ea[8];
    int          Ecnt[8];
    for (int t = 0; t < 8; ++t) {
        ei[t]   = (const int*)d_in[3 + 2 * t];
        ea[t]   = (const float*)d_in[4 + 2 * t];
        Ecnt[t] = in_sizes[3 + 2 * t] / 2;
    }
    const float* Wk    = (const float*)d_in[19];
    const float* bk    = (const float*)d_in[20];
    const float* Wq    = (const float*)d_in[21];
    const float* bq    = (const float*)d_in[22];
    const float* Wv    = (const float*)d_in[23];
    const float* bv    = (const float*)d_in[24];
    const float* Ws    = (const float*)d_in[25];
    const float* bconv = (const float*)d_in[26];
    const float* We    = (const float*)d_in[27];
    const float* be    = (const float*)d_in[28];
    const float* Wgt   = (const float*)d_in[29];
    const float* bgt   = (const float*)d_in[30];
    const float* Wq1   = (const float*)d_in[31];
    const float* Wk2   = (const float*)d_in[32];
    const float* Wv2   = (const float*)d_in[33];
    const float* Wo    = (const float*)d_in[34];
    const float* bo    = (const float*)d_in[35];
    const float* ln_g  = (const float*)d_in[36];
    const float* ln_b  = (const float*)d_in[37];

    // ---- workspace carve-up ----
    char* w = (char*)d_ws;
    ushort* Y[3];
    Y[0] = (ushort*)w; w += (size_t)N_PQ * 1152 * 2;
    Y[1] = (ushort*)w; w += (size_t)N_PV * 1152 * 2;
    Y[2] = (ushort*)w; w += (size_t)N_SL * 768 * 2;
    ushort* xb[3];
    xb[0] = (ushort*)w; w += (size_t)N_PQ * 128 * 2;
    xb[1] = (ushort*)w; w += (size_t)N_PV * 128 * 2;
    xb[2] = (ushort*)w; w += (size_t)N_SL * 128 * 2;
    ushort* panels = (ushort*)w; w += (size_t)786432 * 2;
    ushort* wssum  = (ushort*)w; w += (size_t)98304 * 2;
    ushort* finalw = (ushort*)w; w += (size_t)81920 * 2;
    float* bias_cat = (float*)w; w += 6144 * 4;
    float* bcsum    = (float*)w; w += 768 * 4;
    float* gnode    = (float*)w; w += 16384 * 4;
    ushort* gnodeb  = (ushort*)w; w += 16384 * 2;
    float* k2       = (float*)w; w += 16384 * 4;
    float* v2       = (float*)w; w += 16384 * 4;
    float* pbuf     = (float*)w; w += 1024 * 256 * 4;
    // CSR scratch
    const int NBINS = 262144;   // 245760 used + pad to 1024*256
    int* bins   = (int*)w; w += (size_t)NBINS * 4;
    int* offs   = (int*)w; w += (size_t)NBINS * 4;
    int* cursor = (int*)w; w += (size_t)NBINS * 4;
    int* lsrc   = (int*)w; w += (size_t)600064 * 4;
    int* leid   = (int*)w; w += (size_t)600064 * 4;
    // overlays into Y[0]:
    ushort* gf   = Y[0];
    ushort* qb   = Y[0];
    ushort* ao   = (ushort*)((char*)Y[0] + (size_t)N_PQ * 128 * 2);
    float*  cbuf = (float*)((char*)Y[0] + (size_t)N_PQ * 128 * 4);
    // nw accumulators live in d_out (fp32)
    float* outp = (float*)d_out;
    float* nw[3] = {outp, outp + (size_t)N_PQ * 128, outp + (size_t)(N_PQ + N_PV) * 128};

    const ushort* Wgt_t = finalw;
    const ushort* Wq1_t = finalw + 16384;
    const ushort* Wk2_t = finalw + 32768;
    const ushort* Wv2_t = finalw + 49152;
    const ushort* Wo_t  = finalw + 65536;

    auto gemm_b = [&](const ushort* A, const ushort* Bt, const float* bias,
                      ushort* C, int M, int N) {
        gemm_mfma<1><<<dim3((M + 127) / 128, N / 128), 256, 0, stream>>>(A, Bt, bias, C, M, N);
    };
    auto gemm_f = [&](const ushort* A, const ushort* Bt, const float* bias,
                      float* C, int M, int N) {
        gemm_mfma<0><<<dim3((M + 127) / 128, N / 128), 256, 0, stream>>>(A, Bt, bias, C, M, N);
    };

    // 1) weight prep + input converts
    prep_mats<<<59 * 64, 256, 0, stream>>>(Wk, Wq, Wv, Ws, Wgt, Wq1, Wk2, Wv2, Wo,
                                           panels, wssum, finalw);
    prep_bias<<<6, 256, 0, stream>>>(bk, bq, bv, bconv, bias_cat, bcsum);
    for (int g = 0; g < 3; ++g) {
        int n = NNs[g] * 128;
        f2b_kernel<<<dim3((n / 4 + 255) / 256), 256, 0, stream>>>(xin[g], xb[g], n);
    }

    // 2) CSR build for the 6 non-Slack-dst types: {0,3,6} -> PQ, {1,4,7} -> PV
    const int csr_t[6]    = {0, 3, 6, 1, 4, 7};
    const int csr_base[6] = {0, 65536, 131072, 196608, 212992, 229376};
    HArgs ha;
    {
        int c = 0;
        for (int i = 0; i < 6; ++i) {
            int t = csr_t[i];
            ha.ei[i] = ei[t]; ha.E[i] = Ecnt[t]; ha.base[i] = csr_base[i];
            ha.cum[i] = c; c += Ecnt[t];
        }
        ha.cum[6] = c;
    }
    hipMemsetAsync(bins, 0, (size_t)NBINS * 4, stream);
    hist_kernel<<<dim3((ha.cum[6] + 255) / 256), 256, 0, stream>>>(ha, bins);
    scan_kernel<<<1, 1024, 0, stream>>>(bins, offs);
    hipMemcpyAsync(cursor, offs, (size_t)NBINS * 4, hipMemcpyDeviceToDevice, stream);
    scatter_kernel<<<dim3((ha.cum[6] + 255) / 256), 256, 0, stream>>>(ha, cursor, lsrc, leid);

    // 3) global features + pooling + k2/v2
    gemm_b(xb[0], Wgt_t, bgt, gf, N_PQ, 128);
    gemm_b(xb[1], Wgt_t, bgt, gf + (size_t)N_PQ * 128, N_PV, 128);
    gemm_b(xb[2], Wgt_t, bgt, gf + (size_t)(N_PQ + N_PV) * 128, N_SL, 128);
    pool1<<<1024, 128, 0, stream>>>(gf, pbuf);
    pool2<<<64, 128, 0, stream>>>(pbuf, gnode);
    f2b_kernel<<<dim3(16384 / 4 / 256), 256, 0, stream>>>(gnode, gnodeb, 16384);
    gemm_f(gnodeb, Wk2_t, nullptr, k2, 128, 128);
    gemm_f(gnodeb, Wv2_t, nullptr, v2, 128, 128);

    // 4) two HeteroConv layers
    // gather params:  [g][slot] -> {kcol, src group, qcol, vcol}
    const int g_kcol[2][3] = {{0,128,256},   {0,128,256}};
    const int g_src [2][3] = {{0,1,2},       {0,1,2}};
    const int g_qcol[2][3] = {{384,384,256}, {512,512,384}};
    const int g_vcol[2][3] = {{768,768,512}, {896,896,640}};
    const int g_type[2][3] = {{0,3,6},       {1,4,7}};
    const int kposA[8] = {0, 0, 0, 1, 1, 1, 2, 2};
    const int qposA[8] = {0, 1, 2, 0, 1, 2, 0, 1};
    const int srcsA[8] = {0, 0, 0, 1, 1, 1, 2, 2};
    const int nkgA[3] = {3, 3, 2}, nqgA[3] = {3, 3, 2};

    for (int l = 0; l < 2; ++l) {
        for (int g = 0; g < 3; ++g)
            gemm_b(xb[g], panels + ((size_t)l * 3072 + gofs[g]) * 128,
                   bias_cat + l * 3072 + gofs[g], Y[g], NNs[g], ncol[g]);
        for (int g = 0; g < 3; ++g)
            gemm_f(xb[g], wssum + (size_t)(l * 3 + g) * 16384,
                   bcsum + (l * 3 + g) * 128, nw[g], NNs[g], 128);

        // CSR gathers for PQ and PV destinations
        for (int g = 0; g < 2; ++g) {
            GArgs ga;
            for (int i = 0; i < 3; ++i) {
                int t = g_type[g][i], off = l * 8 + t;
                ga.t[i].base = csr_base[g * 3 + i];
                ga.t[i].kcol = g_kcol[g][i];
                ga.t[i].lds  = ncol[g_src[g][i]];
                ga.t[i].qcol = g_qcol[g][i];
                ga.t[i].vcol = g_vcol[g][i];
                ga.t[i].Ys   = Y[g_src[g][i]];
                ga.t[i].ea   = ea[t];
                ga.t[i].We   = We + (size_t)off * 2048;
                ga.t[i].be   = be + (size_t)off * 128;
            }
            ga.offs = offs; ga.lsrc = lsrc; ga.leid = leid;
            ga.nwg = nw[g]; ga.xbg = xb[g]; ga.Yg = Y[g]; ga.ldg = ncol[g];
            gather_kernel<<<dim3(NNs[g] / 4), 256, 0, stream>>>(ga);
        }

        // Slack destination: tiny atomic path (types 2 and 5) + relu
        for (int ti = 0; ti < 2; ++ti) {
            int t = (ti == 0) ? 2 : 5, s = srcsA[t], off = l * 8 + t;
            const ushort* Yk = Y[2] + kposA[t] * 128;
            const ushort* Yq = Y[s] + (nkgA[s] + qposA[t]) * 128;
            const ushort* Yv = Y[s] + (nkgA[s] + nqgA[s] + qposA[t]) * 128;
            edge_kernel<<<dim3((Ecnt[t] + 1) / 2), 256, 0, stream>>>(
                ei[t], ea[t], We + (size_t)off * 2048, be + (size_t)off * 128,
                Yk, ncol[2], Yq, Yv, ncol[s], nw[2], Ecnt[t]);
        }
        relu_b_kernel<<<dim3(8), 256, 0, stream>>>(nw[2], xb[2], N_SL * 128);
    }

    // 5) cross-attention + residual + LayerNorm
    // PQ
    gemm_b(xb[0], Wq1_t, nullptr, qb, N_PQ, 128);
    attn_kernel<<<dim3(N_PQ / 2), 256, 0, stream>>>(qb, k2, v2, ao, 10, N_PQ);
    gemm_f(ao, Wo_t, bo, cbuf, N_PQ, 128);
    ln_kernel<<<dim3(N_PQ / 4), 256, 0, stream>>>(xb[0], cbuf, ln_g, ln_b, outp, N_PQ);
    // PV
    gemm_b(xb[1], Wq1_t, nullptr, qb, N_PV, 128);
    attn_kernel<<<dim3(N_PV / 2), 256, 0, stream>>>(qb, k2, v2, ao, 8, N_PV);
    gemm_f(ao, Wo_t, bo, cbuf, N_PV, 128);
    ln_kernel<<<dim3(N_PV / 4), 256, 0, stream>>>(xb[1], cbuf, ln_g, ln_b,
                                                  outp + (size_t)N_PQ * 128, N_PV);
    // Slack
    b2f_kernel<<<dim3((N_SL * 128 + 255) / 256), 256, 0, stream>>>(
        xb[2], outp + (size_t)(N_PQ + N_PV) * 128, N_SL * 128);
}

// Round 4
// 985.108 us; speedup vs baseline: 3.0319x; 1.1210x over previous
//
#include <hip/hip_runtime.h>
#include <hip/hip_bf16.h>
#include <math.h>

#define N_PQ 65536
#define N_PV 16384
#define N_SL 64

typedef __attribute__((ext_vector_type(8))) short s16x8;
typedef __attribute__((ext_vector_type(4))) float f32x4;

__device__ __forceinline__ ushort f2bf(float f) {
    union { float f; unsigned u; } x; x.f = f;
    unsigned r = x.u + 0x7fff + ((x.u >> 16) & 1);
    return (ushort)(r >> 16);
}
__device__ __forceinline__ float bf2f(ushort u) {
    union { unsigned u; float f; } x; x.u = ((unsigned)u) << 16;
    return x.f;
}

// ---------------------------------------------------------------------------
// MFMA GEMM: C[M,N] = A[M,128](bf16) @ Bt[N,128](bf16, n-major) + bias
// ---------------------------------------------------------------------------
template<int OUT_BF16>
__global__ __launch_bounds__(256) void gemm_mfma(
    const ushort* __restrict__ A, const ushort* __restrict__ Bt,
    const float* __restrict__ bias, void* __restrict__ Cv, int M, int N)
{
    __shared__ ushort As[128 * 128];
    const int tid = threadIdx.x;
    const int m0 = blockIdx.x * 128;
    const int n0 = blockIdx.y * 128;

    #pragma unroll
    for (int p = 0; p < 8; ++p) {
        int c = p * 256 + tid;
        int row = c >> 4, c16 = c & 15;
        int gr = m0 + row;
        int4 v = make_int4(0, 0, 0, 0);
        if (gr < M) v = *(const int4*)(A + (size_t)gr * 128 + c16 * 8);
        *(int4*)(As + row * 128 + (c16 ^ (row & 7)) * 8) = v;
    }
    __syncthreads();

    const int lane = tid & 63, wave = tid >> 6;
    const int wr = wave >> 1, wc = wave & 1;
    const int lrow = lane & 15, lk = lane >> 4;

    f32x4 acc[4][4];
    #pragma unroll
    for (int mi = 0; mi < 4; ++mi)
        #pragma unroll
        for (int ni = 0; ni < 4; ++ni) acc[mi][ni] = (f32x4){0.f, 0.f, 0.f, 0.f};

    #pragma unroll
    for (int kk = 0; kk < 4; ++kk) {
        s16x8 a[4], b[4];
        #pragma unroll
        for (int mi = 0; mi < 4; ++mi) {
            int row = wr * 64 + mi * 16 + lrow;
            int c16 = (lk + kk * 4) ^ (row & 7);
            a[mi] = *(const s16x8*)(As + row * 128 + c16 * 8);
        }
        #pragma unroll
        for (int ni = 0; ni < 4; ++ni) {
            int n = n0 + wc * 64 + ni * 16 + lrow;
            b[ni] = *(const s16x8*)(Bt + (size_t)n * 128 + kk * 32 + lk * 8);
        }
        #pragma unroll
        for (int mi = 0; mi < 4; ++mi)
            #pragma unroll
            for (int ni = 0; ni < 4; ++ni)
                acc[mi][ni] = __builtin_amdgcn_mfma_f32_16x16x32_bf16(
                    a[mi], b[ni], acc[mi][ni], 0, 0, 0);
    }

    if (OUT_BF16) {
        __syncthreads();
        ushort* Cl = As;
        #pragma unroll
        for (int mi = 0; mi < 4; ++mi)
            #pragma unroll
            for (int ni = 0; ni < 4; ++ni)
                #pragma unroll
                for (int r = 0; r < 4; ++r) {
                    int row = wr * 64 + mi * 16 + (lane >> 4) * 4 + r;
                    int col = wc * 64 + ni * 16 + (lane & 15);
                    float v = acc[mi][ni][r] + (bias ? bias[n0 + col] : 0.f);
                    Cl[row * 128 + (((col >> 3) ^ (row & 7)) << 3) + (col & 7)] = f2bf(v);
                }
        __syncthreads();
        ushort* C = (ushort*)Cv;
        #pragma unroll
        for (int p = 0; p < 8; ++p) {
            int c = p * 256 + tid;
            int row = c >> 4, c16 = c & 15;
            int gr = m0 + row;
            if (gr < M)
                *(int4*)(C + (size_t)gr * N + n0 + c16 * 8) =
                    *(const int4*)(As + row * 128 + (c16 ^ (row & 7)) * 8);
        }
    } else {
        float* C = (float*)Cv;
        #pragma unroll
        for (int mi = 0; mi < 4; ++mi)
            #pragma unroll
            for (int ni = 0; ni < 4; ++ni)
                #pragma unroll
                for (int r = 0; r < 4; ++r) {
                    int row = m0 + wr * 64 + mi * 16 + (lane >> 4) * 4 + r;
                    int col = n0 + wc * 64 + ni * 16 + (lane & 15);
                    if (row < M)
                        C[(size_t)row * N + col] =
                            acc[mi][ni][r] + (bias ? bias[col] : 0.f);
                }
    }
}

// ---------------------------------------------------------------------------
// Weight prep.
// Panel layout per group g (rows of Bt = output cols):
//   [k slots: nk*128] [qv interleaved: nq*256  (q0 q1 v0 v1 per feature pair)]
//   [g<2: ws sum: 128]
// ncol: PQ 1280, PV 1280, SL 768.
// m: 0..51 panels (l=m/26, r=m%26: r<10 g0, r<20 g1, else g2 slot 0..5)
//    52..53 SL wssum, 54..58 final mats.
// ---------------------------------------------------------------------------
__global__ void prep_mats(
    const float* __restrict__ Wk, const float* __restrict__ Wq,
    const float* __restrict__ Wv, const float* __restrict__ Ws,
    const float* __restrict__ Wgt, const float* __restrict__ Wq1,
    const float* __restrict__ Wk2, const float* __restrict__ Wv2,
    const float* __restrict__ Wo,
    ushort* __restrict__ panels, ushort* __restrict__ wssum,
    ushort* __restrict__ finalw)
{
    const int m = blockIdx.x >> 6;
    const int e = (blockIdx.x & 63) * 256 + threadIdx.x;
    const int nl = e >> 7, k = e & 127;
    const int dstlist[3][3] = {{0,3,6},{1,4,7},{2,5,-1}};
    const int srclist[3][3] = {{0,1,2},{3,4,5},{6,7,-1}};
    const int nkg[3] = {3,3,2};
    const int gofs[3] = {0,1280,2560};

    if (m < 52) {
        int l = m / 26, r = m % 26;
        int g, slot;
        if (r < 10)      { g = 0; slot = r; }
        else if (r < 20) { g = 1; slot = r - 10; }
        else             { g = 2; slot = r - 20; }
        int nk = nkg[g];
        float val; int col;
        if (slot < nk) {
            int t = dstlist[g][slot];
            val = Wk[(size_t)(l * 8 + t) * 16384 + k * 128 + nl];
            col = slot * 128 + nl;
        } else if (slot < 2 * nk) {
            int s = slot - nk; int t = srclist[g][s];
            val = Wq[(size_t)(l * 8 + t) * 16384 + k * 128 + nl];
            col = nk * 128 + s * 256 + ((nl >> 1) << 2) + (nl & 1);
        } else if (slot < 3 * nk) {
            int s = slot - 2 * nk; int t = srclist[g][s];
            val = Wv[(size_t)(l * 8 + t) * 16384 + k * 128 + nl];
            col = nk * 128 + s * 256 + ((nl >> 1) << 2) + 2 + (nl & 1);
        } else {  // ws sum (g<2 only)
            float s = 0.f;
            #pragma unroll
            for (int i = 0; i < 3; ++i) {
                int t = dstlist[g][i];
                if (t >= 0) s += Ws[(size_t)(l * 8 + t) * 16384 + k * 128 + nl];
            }
            val = s; col = 1152 + nl;
        }
        panels[((size_t)l * 3328 + gofs[g] + col) * 128 + k] = f2bf(val);
    } else if (m < 54) {
        int l = m - 52;
        float s = Ws[(size_t)(l * 8 + 2) * 16384 + k * 128 + nl]
                + Ws[(size_t)(l * 8 + 5) * 16384 + k * 128 + nl];
        wssum[(size_t)l * 16384 + nl * 128 + k] = f2bf(s);
    } else {
        const float* fsrc[5] = {Wgt, Wq1, Wk2, Wv2, Wo};
        int idx = m - 54;
        finalw[(size_t)idx * 16384 + nl * 128 + k] = f2bf(fsrc[idx][k * 128 + nl]);
    }
}

__global__ void prep_bias(
    const float* __restrict__ bk, const float* __restrict__ bq,
    const float* __restrict__ bv, const float* __restrict__ bconv,
    float* __restrict__ bias_cat, float* __restrict__ bcsum)
{
    const int l = blockIdx.x / 3, g = blockIdx.x % 3;
    const int dstlist[3][3] = {{0,3,6},{1,4,7},{2,5,-1}};
    const int srclist[3][3] = {{0,1,2},{3,4,5},{6,7,-1}};
    const int nkg[3] = {3,3,2};
    const int gofs[3] = {0,1280,2560};
    const int nslots = (g < 2) ? 10 : 6;
    int nk = nkg[g];
    for (int idx = threadIdx.x; idx < nslots * 128; idx += 256) {
        int slot = idx >> 7, nl = idx & 127;
        float val; int col;
        if (slot < nk) {
            int t = dstlist[g][slot];
            val = bk[(l * 8 + t) * 128 + nl];
            col = slot * 128 + nl;
        } else if (slot < 2 * nk) {
            int s = slot - nk; int t = srclist[g][s];
            val = bq[(l * 8 + t) * 128 + nl];
            col = nk * 128 + s * 256 + ((nl >> 1) << 2) + (nl & 1);
        } else if (slot < 3 * nk) {
            int s = slot - 2 * nk; int t = srclist[g][s];
            val = bv[(l * 8 + t) * 128 + nl];
            col = nk * 128 + s * 256 + ((nl >> 1) << 2) + 2 + (nl & 1);
        } else {
            float s = 0.f;
            #pragma unroll
            for (int i = 0; i < 3; ++i) {
                int t = dstlist[g][i];
                if (t >= 0) s += bconv[(l * 8 + t) * 128 + nl];
            }
            val = s; col = 1152 + nl;
        }
        bias_cat[l * 3328 + gofs[g] + col] = val;
    }
    if (g == 2 && threadIdx.x < 128) {
        bcsum[l * 128 + threadIdx.x] =
            bconv[(l * 8 + 2) * 128 + threadIdx.x] + bconv[(l * 8 + 5) * 128 + threadIdx.x];
    }
}

// ---------------------------------------------------------------------------
// CSR build: histogram -> parallel scan (3 kernels) -> scatter
// ---------------------------------------------------------------------------
struct HArgs {
    const int* ei[6];
    int E[6];
    int base[6];
    int cum[7];
};

__global__ void hist_kernel(HArgs A, int* __restrict__ bins)
{
    int g = blockIdx.x * 256 + threadIdx.x;
    if (g >= A.cum[6]) return;
    int t = 0;
    #pragma unroll
    for (int i = 0; i < 5; ++i) t += (g >= A.cum[i + 1]);
    int e = g - A.cum[t];
    int dst = A.ei[t][A.E[t] + e];
    atomicAdd(&bins[A.base[t] + dst], 1);
}

__global__ __launch_bounds__(256) void scan_a(
    const int* __restrict__ bins, int* __restrict__ offs, int* __restrict__ bsum)
{
    __shared__ int s[256];
    const int b = blockIdx.x, t = threadIdx.x;
    int v = bins[b * 256 + t];
    s[t] = v; __syncthreads();
    #pragma unroll
    for (int off = 1; off < 256; off <<= 1) {
        int x = (t >= off) ? s[t - off] : 0;
        __syncthreads();
        s[t] += x;
        __syncthreads();
    }
    offs[b * 256 + t] = s[t] - v;
    if (t == 255) bsum[b] = s[255];
}

__global__ __launch_bounds__(1024) void scan_b(
    const int* __restrict__ bsum, int* __restrict__ carry)
{
    __shared__ int s[1024];
    const int t = threadIdx.x;
    int v = bsum[t];
    s[t] = v; __syncthreads();
    for (int off = 1; off < 1024; off <<= 1) {
        int x = (t >= off) ? s[t - off] : 0;
        __syncthreads();
        s[t] += x;
        __syncthreads();
    }
    carry[t] = s[t] - v;
}

__global__ void scan_c(int* __restrict__ offs, const int* __restrict__ carry,
                       int* __restrict__ cursor)
{
    const int b = blockIdx.x, t = threadIdx.x;
    int v = offs[b * 256 + t] + carry[b];
    offs[b * 256 + t] = v;
    cursor[b * 256 + t] = v;
}

__global__ void scatter_kernel(HArgs A, int* __restrict__ cursor,
                               int* __restrict__ lsrc, int* __restrict__ leid)
{
    int g = blockIdx.x * 256 + threadIdx.x;
    if (g >= A.cum[6]) return;
    int t = 0;
    #pragma unroll
    for (int i = 0; i < 5; ++i) t += (g >= A.cum[i + 1]);
    int e = g - A.cum[t];
    int src = A.ei[t][e];
    int dst = A.ei[t][A.E[t] + e];
    int pos = atomicAdd(&cursor[A.base[t] + dst], 1);
    lsrc[pos] = src;
    leid[pos] = e;
}

// ---------------------------------------------------------------------------
// CSR gather: one wave per dst node, 2 features/lane, 3 incoming types.
// qv interleaved -> single ushort4 scattered load per edge; software-pipelined.
// acc init from ws column of Yg; fused ReLU + bf16 store. No atomics.
// ---------------------------------------------------------------------------
struct GTA {
    int base, kcol, qvcol, lds;
    const ushort* Ys;
    const float* ea;
    const float* We;
    const float* be;
};
struct GArgs {
    GTA t[3];
    const int* offs;
    const int* lsrc;
    const int* leid;
    ushort* xbg;
    const ushort* Yg;
    int ldg, wscol;
};

__global__ __launch_bounds__(256) void gather_kernel(GArgs A)
{
    const int wave = threadIdx.x >> 6, lane = threadIdx.x & 63;
    const int d = blockIdx.x * 4 + wave;
    const int j0 = lane * 2;

    ushort2 w2 = *(const ushort2*)(A.Yg + (size_t)d * A.ldg + A.wscol + j0);
    float a0 = bf2f(w2.x), a1 = bf2f(w2.y);

    #pragma unroll
    for (int i = 0; i < 3; ++i) {
        const GTA T = A.t[i];
        int start = __builtin_amdgcn_readfirstlane(A.offs[T.base + d]);
        int end   = __builtin_amdgcn_readfirstlane(A.offs[T.base + d + 1]);
        if (start == end) continue;

        ushort2 kk = *(const ushort2*)(A.Yg + (size_t)d * A.ldg + T.kcol + j0);
        float k0 = bf2f(kk.x), k1 = bf2f(kk.y);
        float we0[16], we1[16];
        #pragma unroll
        for (int r = 0; r < 16; ++r) {
            float2 wv = *(const float2*)(T.We + r * 128 + j0);
            we0[r] = wv.x; we1[r] = wv.y;
        }
        float2 be2 = *(const float2*)(T.be + j0);

        int si  = __builtin_amdgcn_readfirstlane(A.lsrc[start]);
        int eid = __builtin_amdgcn_readfirstlane(A.leid[start]);
        uint2 qv = *(const uint2*)(T.Ys + (size_t)si * T.lds + T.qvcol + lane * 4);
        float4 eA = *(const float4*)(T.ea + (size_t)eid * 16);
        float4 eB = *(const float4*)(T.ea + (size_t)eid * 16 + 4);
        float4 eC = *(const float4*)(T.ea + (size_t)eid * 16 + 8);
        float4 eD = *(const float4*)(T.ea + (size_t)eid * 16 + 12);

        for (int e = start; e < end; ++e) {
            int nx = (e + 1 < end) ? (e + 1) : e;
            int si_n  = __builtin_amdgcn_readfirstlane(A.lsrc[nx]);
            int eid_n = __builtin_amdgcn_readfirstlane(A.leid[nx]);
            uint2 qv_n = *(const uint2*)(T.Ys + (size_t)si_n * T.lds + T.qvcol + lane * 4);
            float4 nA = *(const float4*)(T.ea + (size_t)eid_n * 16);
            float4 nB = *(const float4*)(T.ea + (size_t)eid_n * 16 + 4);
            float4 nC = *(const float4*)(T.ea + (size_t)eid_n * 16 + 8);
            float4 nD = *(const float4*)(T.ea + (size_t)eid_n * 16 + 12);

            float e0 = be2.x, e1 = be2.y;
            e0 += eA.x*we0[0] + eA.y*we0[1] + eA.z*we0[2] + eA.w*we0[3]
                + eB.x*we0[4] + eB.y*we0[5] + eB.z*we0[6] + eB.w*we0[7]
                + eC.x*we0[8] + eC.y*we0[9] + eC.z*we0[10] + eC.w*we0[11]
                + eD.x*we0[12] + eD.y*we0[13] + eD.z*we0[14] + eD.w*we0[15];
            e1 += eA.x*we1[0] + eA.y*we1[1] + eA.z*we1[2] + eA.w*we1[3]
                + eB.x*we1[4] + eB.y*we1[5] + eB.z*we1[6] + eB.w*we1[7]
                + eC.x*we1[8] + eC.y*we1[9] + eC.z*we1[10] + eC.w*we1[11]
                + eD.x*we1[12] + eD.y*we1[13] + eD.z*we1[14] + eD.w*we1[15];
            float q0 = bf2f((ushort)(qv.x & 0xffff)), q1 = bf2f((ushort)(qv.x >> 16));
            float v0 = bf2f((ushort)(qv.y & 0xffff)), v1 = bf2f((ushort)(qv.y >> 16));
            float g0 = 1.f / (1.f + __expf(-(k0 + q0 + e0)));
            float g1 = 1.f / (1.f + __expf(-(k1 + q1 + e1)));
            a0 += g0 * v0;
            a1 += g1 * v1;
            qv = qv_n; eA = nA; eB = nB; eC = nC; eD = nD;
        }
    }
    ushort2 o; o.x = f2bf(fmaxf(a0, 0.f)); o.y = f2bf(fmaxf(a1, 0.f));
    *(ushort2*)(A.xbg + (size_t)d * 128 + j0) = o;
}

// ---------------------------------------------------------------------------
// Atomic edge kernel for Slack-destination types (qv interleaved layout)
// ---------------------------------------------------------------------------
__global__ __launch_bounds__(256) void edge_slack(
    const int* __restrict__ ei, const float* __restrict__ ea,
    const float* __restrict__ We, const float* __restrict__ be,
    const ushort* __restrict__ Yk, int ldk,
    const ushort* __restrict__ Yqv, int ldq,
    float* __restrict__ nd, int E)
{
    const int e = blockIdx.x * 2 + (threadIdx.x >> 7);
    if (e >= E) return;
    const int j = threadIdx.x & 127;
    const int si = ei[e];
    const int di = ei[E + e];

    float ej = be[j];
    #pragma unroll
    for (int r = 0; r < 16; ++r)
        ej += ea[(size_t)e * 16 + r] * We[r * 128 + j];

    float kv = bf2f(Yk[(size_t)di * ldk + j]);
    float qv = bf2f(Yqv[(size_t)si * ldq + ((j >> 1) << 2) + (j & 1)]);
    float vv = bf2f(Yqv[(size_t)si * ldq + ((j >> 1) << 2) + 2 + (j & 1)]);
    float g  = 1.f / (1.f + __expf(-(kv + qv + ej)));
    atomicAdd(&nd[(size_t)di * 128 + j], g * vv);
}

// ---------------------------------------------------------------------------
// Elementwise helpers
// ---------------------------------------------------------------------------
__global__ void f2b_kernel(const float* __restrict__ a, ushort* __restrict__ o, int n)
{
    int i = (blockIdx.x * 256 + threadIdx.x) * 4;
    if (i < n) {
        float4 v = *(const float4*)(a + i);
        ushort4 u; u.x = f2bf(v.x); u.y = f2bf(v.y); u.z = f2bf(v.z); u.w = f2bf(v.w);
        *(ushort4*)(o + i) = u;
    }
}
__global__ void relu_b_kernel(const float* __restrict__ a, ushort* __restrict__ o, int n)
{
    int i = (blockIdx.x * 256 + threadIdx.x) * 4;
    if (i < n) {
        float4 v = *(const float4*)(a + i);
        ushort4 u;
        u.x = f2bf(fmaxf(v.x, 0.f)); u.y = f2bf(fmaxf(v.y, 0.f));
        u.z = f2bf(fmaxf(v.z, 0.f)); u.w = f2bf(fmaxf(v.w, 0.f));
        *(ushort4*)(o + i) = u;
    }
}
__global__ void b2f_kernel(const ushort* __restrict__ a, float* __restrict__ o, int n)
{
    int i = blockIdx.x * 256 + threadIdx.x;
    if (i < n) o[i] = bf2f(a[i]);
}

// ---------------------------------------------------------------------------
// Global pooling over gf (bf16): two-stage mean+max
// ---------------------------------------------------------------------------
__global__ void pool1(const ushort* __restrict__ gf, float* __restrict__ pbuf)
{
    const int b = blockIdx.x >> 4, c = blockIdx.x & 15;
    const int j = threadIdx.x;
    float s = 0.f, m = -INFINITY;
    const ushort* pq = gf + (size_t)(b * 1024 + c * 64) * 128;
    for (int i = 0; i < 64; ++i) { float v = bf2f(pq[i * 128 + j]); s += v; m = fmaxf(m, v); }
    const ushort* pv = gf + (size_t)(N_PQ + b * 256 + c * 16) * 128;
    for (int i = 0; i < 16; ++i) { float v = bf2f(pv[i * 128 + j]); s += v; m = fmaxf(m, v); }
    if (c == 0) { float v = bf2f(gf[(size_t)(N_PQ + N_PV + b) * 128 + j]); s += v; m = fmaxf(m, v); }
    pbuf[(size_t)blockIdx.x * 256 + j] = s;
    pbuf[(size_t)blockIdx.x * 256 + 128 + j] = m;
}
__global__ void pool2(const float* __restrict__ pbuf, float* __restrict__ gnode)
{
    const int b = blockIdx.x, j = threadIdx.x;
    float s = 0.f, m = -INFINITY;
    for (int c = 0; c < 16; ++c) {
        s += pbuf[(size_t)(b * 16 + c) * 256 + j];
        m = fmaxf(m, pbuf[(size_t)(b * 16 + c) * 256 + 128 + j]);
    }
    gnode[(size_t)(b * 2) * 128 + j]     = s * (1.f / 1281.f);
    gnode[(size_t)(b * 2 + 1) * 128 + j] = m;
}

// ---------------------------------------------------------------------------
// Cross-attention (2 keys)
// ---------------------------------------------------------------------------
__global__ __launch_bounds__(256) void attn_kernel(
    const ushort* __restrict__ q, const float* __restrict__ k2,
    const float* __restrict__ v2, ushort* __restrict__ ao, int shift, int Ntot)
{
    const int n = blockIdx.x * 2 + (threadIdx.x >> 7);
    if (n >= Ntot) return;
    const int j = threadIdx.x & 127;
    const int b = n >> shift;
    const int h16 = j & ~15;

    const ushort* qn = q + (size_t)n * 128 + h16;
    const float* k0 = k2 + (size_t)(b * 2) * 128 + h16;
    const float* k1 = k2 + (size_t)(b * 2 + 1) * 128 + h16;
    float s0 = 0.f, s1 = 0.f;
    #pragma unroll
    for (int d = 0; d < 16; ++d) {
        float qq = bf2f(qn[d]); s0 += qq * k0[d]; s1 += qq * k1[d];
    }
    s0 *= 0.25f; s1 *= 0.25f;
    float m  = fmaxf(s0, s1);
    float a0 = __expf(s0 - m), a1 = __expf(s1 - m);
    float inv = 1.f / (a0 + a1);
    ao[(size_t)n * 128 + j] = f2bf(
        (a0 * v2[(size_t)(b * 2) * 128 + j] + a1 * v2[(size_t)(b * 2 + 1) * 128 + j]) * inv);
}

// ---------------------------------------------------------------------------
// LayerNorm
// ---------------------------------------------------------------------------
__global__ __launch_bounds__(256) void ln_kernel(
    const ushort* __restrict__ x, const float* __restrict__ ca,
    const float* __restrict__ g, const float* __restrict__ bb,
    float* __restrict__ out, int N)
{
    const int n = blockIdx.x * 4 + (threadIdx.x >> 6);
    if (n >= N) return;
    const int l = threadIdx.x & 63;
    const size_t base = (size_t)n * 128;
    float h0 = bf2f(x[base + l * 2])     + ca[base + l * 2];
    float h1 = bf2f(x[base + l * 2 + 1]) + ca[base + l * 2 + 1];
    float s  = h0 + h1;
    float ss = h0 * h0 + h1 * h1;
    #pragma unroll
    for (int o = 32; o; o >>= 1) { s += __shfl_xor(s, o); ss += __shfl_xor(ss, o); }
    float mu  = s * (1.f / 128.f);
    float var = ss * (1.f / 128.f) - mu * mu;
    float rs  = rsqrtf(var + 1e-5f);
    out[base + l * 2]     = (h0 - mu) * rs * g[l * 2]     + bb[l * 2];
    out[base + l * 2 + 1] = (h1 - mu) * rs * g[l * 2 + 1] + bb[l * 2 + 1];
}

// ---------------------------------------------------------------------------
// Host orchestration
// ---------------------------------------------------------------------------
extern "C" void kernel_launch(void* const* d_in, const int* in_sizes, int n_in,
                              void* d_out, int out_size, void* d_ws, size_t ws_size,
                              hipStream_t stream)
{
    const float* xin[3] = {(const float*)d_in[0], (const float*)d_in[1], (const float*)d_in[2]};
    const int NNs[3] = {N_PQ, N_PV, N_SL};
    const int ncol[3] = {1280, 1280, 768};
    const int gofs[3] = {0, 1280, 2560};

    const int*   ei[8];
    const float* ea[8];
    int          Ecnt[8];
    for (int t = 0; t < 8; ++t) {
        ei[t]   = (const int*)d_in[3 + 2 * t];
        ea[t]   = (const float*)d_in[4 + 2 * t];
        Ecnt[t] = in_sizes[3 + 2 * t] / 2;
    }
    const float* Wk    = (const float*)d_in[19];
    const float* bk    = (const float*)d_in[20];
    const float* Wq    = (const float*)d_in[21];
    const float* bq    = (const float*)d_in[22];
    const float* Wv    = (const float*)d_in[23];
    const float* bv    = (const float*)d_in[24];
    const float* Ws    = (const float*)d_in[25];
    const float* bconv = (const float*)d_in[26];
    const float* We    = (const float*)d_in[27];
    const float* be    = (const float*)d_in[28];
    const float* Wgt   = (const float*)d_in[29];
    const float* bgt   = (const float*)d_in[30];
    const float* Wq1   = (const float*)d_in[31];
    const float* Wk2   = (const float*)d_in[32];
    const float* Wv2   = (const float*)d_in[33];
    const float* Wo    = (const float*)d_in[34];
    const float* bo    = (const float*)d_in[35];
    const float* ln_g  = (const float*)d_in[36];
    const float* ln_b  = (const float*)d_in[37];

    // ---- workspace carve-up ----
    char* w = (char*)d_ws;
    ushort* Y[3];
    Y[0] = (ushort*)w; w += (size_t)N_PQ * 1280 * 2;
    Y[1] = (ushort*)w; w += (size_t)N_PV * 1280 * 2;
    Y[2] = (ushort*)w; w += (size_t)N_SL * 768 * 2;
    ushort* xb[3];
    xb[0] = (ushort*)w; w += (size_t)N_PQ * 128 * 2;
    xb[1] = (ushort*)w; w += (size_t)N_PV * 128 * 2;
    xb[2] = (ushort*)w; w += (size_t)N_SL * 128 * 2;
    ushort* panels = (ushort*)w; w += (size_t)2 * 3328 * 128 * 2;
    ushort* wssum  = (ushort*)w; w += (size_t)2 * 16384 * 2;
    ushort* finalw = (ushort*)w; w += (size_t)5 * 16384 * 2;
    float* bias_cat = (float*)w; w += 6656 * 4;
    float* bcsum    = (float*)w; w += 256 * 4;
    float* gnode    = (float*)w; w += 16384 * 4;
    ushort* gnodeb  = (ushort*)w; w += 16384 * 2;
    float* k2       = (float*)w; w += 16384 * 4;
    float* v2       = (float*)w; w += 16384 * 4;
    float* pbuf     = (float*)w; w += 1024 * 256 * 4;
    // CSR scratch
    const int NBINS = 262144;   // 1024 x 256; 245760 used
    int* bins   = (int*)w; w += (size_t)NBINS * 4;
    int* offs   = (int*)w; w += (size_t)NBINS * 4;
    int* cursor = (int*)w; w += (size_t)NBINS * 4;
    int* bsum   = (int*)w; w += 1024 * 4;
    int* carry  = (int*)w; w += 1024 * 4;
    int* lsrc   = (int*)w; w += (size_t)600064 * 4;
    int* leid   = (int*)w; w += (size_t)600064 * 4;
    // overlays into Y[0]:
    ushort* gf   = Y[0];
    ushort* qb   = Y[0];
    ushort* ao   = (ushort*)((char*)Y[0] + (size_t)N_PQ * 128 * 2);
    float*  cbuf = (float*)((char*)Y[0] + (size_t)N_PQ * 128 * 4);
    float* outp = (float*)d_out;
    float* nw2 = outp + (size_t)(N_PQ + N_PV) * 128;   // Slack fp32 accumulator

    const ushort* Wgt_t = finalw;
    const ushort* Wq1_t = finalw + 16384;
    const ushort* Wk2_t = finalw + 32768;
    const ushort* Wv2_t = finalw + 49152;
    const ushort* Wo_t  = finalw + 65536;

    auto gemm_b = [&](const ushort* A, const ushort* Bt, const float* bias,
                      ushort* C, int M, int N) {
        gemm_mfma<1><<<dim3((M + 127) / 128, N / 128), 256, 0, stream>>>(A, Bt, bias, C, M, N);
    };
    auto gemm_f = [&](const ushort* A, const ushort* Bt, const float* bias,
                      float* C, int M, int N) {
        gemm_mfma<0><<<dim3((M + 127) / 128, N / 128), 256, 0, stream>>>(A, Bt, bias, C, M, N);
    };

    // 1) weight prep + input converts
    prep_mats<<<59 * 64, 256, 0, stream>>>(Wk, Wq, Wv, Ws, Wgt, Wq1, Wk2, Wv2, Wo,
                                           panels, wssum, finalw);
    prep_bias<<<6, 256, 0, stream>>>(bk, bq, bv, bconv, bias_cat, bcsum);
    for (int g = 0; g < 3; ++g) {
        int n = NNs[g] * 128;
        f2b_kernel<<<dim3((n / 4 + 255) / 256), 256, 0, stream>>>(xin[g], xb[g], n);
    }

    // 2) CSR build: {0,3,6} -> PQ bins, {1,4,7} -> PV bins
    const int csr_t[6]    = {0, 3, 6, 1, 4, 7};
    const int csr_base[6] = {0, 65536, 131072, 196608, 212992, 229376};
    HArgs ha;
    {
        int c = 0;
        for (int i = 0; i < 6; ++i) {
            int t = csr_t[i];
            ha.ei[i] = ei[t]; ha.E[i] = Ecnt[t]; ha.base[i] = csr_base[i];
            ha.cum[i] = c; c += Ecnt[t];
        }
        ha.cum[6] = c;
    }
    hipMemsetAsync(bins, 0, (size_t)NBINS * 4, stream);
    hist_kernel<<<dim3((ha.cum[6] + 255) / 256), 256, 0, stream>>>(ha, bins);
    scan_a<<<1024, 256, 0, stream>>>(bins, offs, bsum);
    scan_b<<<1, 1024, 0, stream>>>(bsum, carry);
    scan_c<<<1024, 256, 0, stream>>>(offs, carry, cursor);
    scatter_kernel<<<dim3((ha.cum[6] + 255) / 256), 256, 0, stream>>>(ha, cursor, lsrc, leid);

    // 3) global features + pooling + k2/v2
    gemm_b(xb[0], Wgt_t, bgt, gf, N_PQ, 128);
    gemm_b(xb[1], Wgt_t, bgt, gf + (size_t)N_PQ * 128, N_PV, 128);
    gemm_b(xb[2], Wgt_t, bgt, gf + (size_t)(N_PQ + N_PV) * 128, N_SL, 128);
    pool1<<<1024, 128, 0, stream>>>(gf, pbuf);
    pool2<<<64, 128, 0, stream>>>(pbuf, gnode);
    f2b_kernel<<<dim3(16384 / 4 / 256), 256, 0, stream>>>(gnode, gnodeb, 16384);
    gemm_f(gnodeb, Wk2_t, nullptr, k2, 128, 128);
    gemm_f(gnodeb, Wv2_t, nullptr, v2, 128, 128);

    // 4) two HeteroConv layers
    for (int l = 0; l < 2; ++l) {
        for (int g = 0; g < 3; ++g)
            gemm_b(xb[g], panels + ((size_t)l * 3328 + gofs[g]) * 128,
                   bias_cat + l * 3328 + gofs[g], Y[g], NNs[g], ncol[g]);
        gemm_f(xb[2], wssum + (size_t)l * 16384, bcsum + l * 128, nw2, N_SL, 128);

        // CSR gathers for PQ and PV destinations
        for (int g = 0; g < 2; ++g) {
            GArgs ga;
            for (int i = 0; i < 3; ++i) {
                int t = csr_t[g * 3 + i], off = l * 8 + t;
                int sgrp = (i == 2) ? 2 : i;   // src groups: {0,1,2} for both g
                ga.t[i].base  = csr_base[g * 3 + i];
                ga.t[i].kcol  = i * 128;
                ga.t[i].lds   = ncol[sgrp];
                // qv block: src-group slot of this type (g is the dst): slot==g for PQ/PV srcs,
                // slot==g for Slack src; nk*128 + slot*256
                ga.t[i].qvcol = ((sgrp == 2) ? 256 : 384) + g * 256;
                ga.t[i].Ys    = Y[sgrp];
                ga.t[i].ea    = ea[t];
                ga.t[i].We    = We + (size_t)off * 2048;
                ga.t[i].be    = be + (size_t)off * 128;
            }
            ga.offs = offs; ga.lsrc = lsrc; ga.leid = leid;
            ga.xbg = xb[g]; ga.Yg = Y[g]; ga.ldg = ncol[g]; ga.wscol = 1152;
            gather_kernel<<<dim3(NNs[g] / 4), 256, 0, stream>>>(ga);
        }

        // Slack destination: tiny atomic path (types 2 and 5) + relu
        {
            int off2 = l * 8 + 2;
            edge_slack<<<dim3((Ecnt[2] + 1) / 2), 256, 0, stream>>>(
                ei[2], ea[2], We + (size_t)off2 * 2048, be + (size_t)off2 * 128,
                Y[2] + 0, 768, Y[0] + 896, 1280, nw2, Ecnt[2]);
            int off5 = l * 8 + 5;
            edge_slack<<<dim3((Ecnt[5] + 1) / 2), 256, 0, stream>>>(
                ei[5], ea[5], We + (size_t)off5 * 2048, be + (size_t)off5 * 128,
                Y[2] + 128, 768, Y[1] + 896, 1280, nw2, Ecnt[5]);
        }
        relu_b_kernel<<<dim3(8), 256, 0, stream>>>(nw2, xb[2], N_SL * 128);
    }

    // 5) cross-attention + residual + LayerNorm
    // PQ
    gemm_b(xb[0], Wq1_t, nullptr, qb, N_PQ, 128);
    attn_kernel<<<dim3(N_PQ / 2), 256, 0, stream>>>(qb, k2, v2, ao, 10, N_PQ);
    gemm_f(ao, Wo_t, bo, cbuf, N_PQ, 128);
    ln_kernel<<<dim3(N_PQ / 4), 256, 0, stream>>>(xb[0], cbuf, ln_g, ln_b, outp, N_PQ);
    // PV
    gemm_b(xb[1], Wq1_t, nullptr, qb, N_PV, 128);
    attn_kernel<<<dim3(N_PV / 2), 256, 0, stream>>>(qb, k2, v2, ao, 8, N_PV);
    gemm_f(ao, Wo_t, bo, cbuf, N_PV, 128);
    ln_kernel<<<dim3(N_PV / 4), 256, 0, stream>>>(xb[1], cbuf, ln_g, ln_b,
                                                  outp + (size_t)N_PQ * 128, N_PV);
    // Slack
    b2f_kernel<<<dim3((N_SL * 128 + 255) / 256), 256, 0, stream>>>(
        xb[2], outp + (size_t)(N_PQ + N_PV) * 128, N_SL * 128);
}